// Round 2
// baseline (2899.811 us; speedup 1.0000x reference)
//
#include <hip/hip_runtime.h>
#include <hip/hip_bf16.h>
#include <stdint.h>

#define BF16 __hip_bfloat16

typedef __attribute__((ext_vector_type(8))) short short8;
typedef __attribute__((ext_vector_type(4))) float floatx4;

typedef const __attribute__((address_space(1))) void* gas_cvp;
typedef __attribute__((address_space(3))) void* las_vp;

__device__ __forceinline__ float bf2f(BF16 v) { return __bfloat162float(v); }
__device__ __forceinline__ BF16 f2bf(float v) { return __float2bfloat16(v); }

// ---------------------------------------------------------------------------
// Weight fp32 [K,N] -> bf16 transposed [N,K]
// ---------------------------------------------------------------------------
__global__ __launch_bounds__(256) void wtrans(const float* __restrict__ W,
                                              BF16* __restrict__ Wt, int K, int N) {
    __shared__ float t[32][33];
    int k0 = blockIdx.x * 32, n0 = blockIdx.y * 32;
    int tx = threadIdx.x & 31, ty = threadIdx.x >> 5;  // ty 0..7
#pragma unroll
    for (int i = 0; i < 32; i += 8) t[ty + i][tx] = W[(size_t)(k0 + ty + i) * N + n0 + tx];
    __syncthreads();
#pragma unroll
    for (int i = 0; i < 32; i += 8)
        Wt[(size_t)(n0 + ty + i) * K + k0 + tx] = f2bf(t[tx][ty + i]);
}

// ---------------------------------------------------------------------------
// LayerNorm over 768 cols, block=256.
// MODE 0: rows of x[:,1:,:]  -> bf16
// MODE 1: spatial xs rows (cls from x / patch from xtfull fp32) -> bf16
// MODE 2: plain fp32 rows -> bf16
// MODE 3: cls rows (row*197) of bf16 src -> fp32
// ---------------------------------------------------------------------------
template <int MODE>
__global__ __launch_bounds__(256) void ln_kernel(const float* __restrict__ src0,
                                                 const float* __restrict__ src1,
                                                 const BF16* __restrict__ srcb,
                                                 const float* __restrict__ g,
                                                 const float* __restrict__ bta,
                                                 BF16* __restrict__ dst_bf,
                                                 float* __restrict__ dst_f) {
    const int r = blockIdx.x, tid = threadIdx.x;
    float x0, x1, x2;
    if (MODE == 3) {
        const BF16* src = srcb + (size_t)r * 197 * 768;
        x0 = bf2f(src[tid]); x1 = bf2f(src[tid + 256]); x2 = bf2f(src[tid + 512]);
    } else {
        const float* src;
        if (MODE == 0) {
            int b = r / 3136, rr = r - b * 3136;
            src = src0 + ((size_t)b * 3137 + 1 + rr) * 768;
        } else if (MODE == 1) {
            int bt = r / 197, j = r - bt * 197;
            int b = bt >> 4, t = bt & 15;
            if (j == 0) src = src0 + (size_t)b * 3137 * 768;
            else        src = src1 + ((size_t)b * 3136 + (size_t)(j - 1) * 16 + t) * 768;
        } else {
            src = src0 + (size_t)r * 768;
        }
        x0 = src[tid]; x1 = src[tid + 256]; x2 = src[tid + 512];
    }
    float s = x0 + x1 + x2;
    float ss = x0 * x0 + x1 * x1 + x2 * x2;
    __shared__ float red[8];
#pragma unroll
    for (int o = 32; o > 0; o >>= 1) { s += __shfl_down(s, o); ss += __shfl_down(ss, o); }
    if ((tid & 63) == 0) { red[tid >> 6] = s; red[4 + (tid >> 6)] = ss; }
    __syncthreads();
    s = red[0] + red[1] + red[2] + red[3];
    ss = red[4] + red[5] + red[6] + red[7];
    const float mu = s * (1.0f / 768.0f);
    const float var = ss * (1.0f / 768.0f) - mu * mu;
    const float rstd = rsqrtf(var + 1e-5f);
#pragma unroll
    for (int i = 0; i < 3; ++i) {
        int c = tid + i * 256;
        float xv = (i == 0) ? x0 : (i == 1) ? x1 : x2;
        float y = (xv - mu) * rstd * g[c] + bta[c];
        if (MODE == 3) dst_f[(size_t)r * 768 + c] = y;
        else           dst_bf[(size_t)r * 768 + c] = f2bf(y);
    }
}

// ---------------------------------------------------------------------------
// bf16 GEMM: C[M,N] = A'[M,K] @ Bt[N,K]^T with row-mapped A and fused epilogue.
// AMAP: 0 identity; 1 scale8 (r -> (r>>3)*16+8+(r&7)); 2 scale4 (r -> (r>>2)*16+12+(r&3))
// OMODE: 0 bf16 plain; 1 bf16 +bias; 2 merge8 RMW; 3 merge4 RMW;
//        4 fp32 +bias +x-residual(CLS-skip rows); 6 bf16 +bias+gelu; 7 fp32 +bias+res
// ---------------------------------------------------------------------------
template <int AMAP, int OMODE>
__global__ __launch_bounds__(256) void gemm_bf16(const BF16* __restrict__ A,
                                                 const BF16* __restrict__ Bt,
                                                 const float* __restrict__ bias,
                                                 const void* __restrict__ res,
                                                 void* __restrict__ Cout,
                                                 int M, int N, int K) {
    __shared__ BF16 Al[128 * 32];
    __shared__ BF16 Bl[128 * 32];
    const int tid = threadIdx.x;
    const int lane = tid & 63;
    const int w = tid >> 6;
    const int bm0 = blockIdx.x * 128;
    const int bn0 = blockIdx.y * 128;

    const BF16* gsrc[4];
    BF16* ldst[4];
#pragma unroll
    for (int j = 0; j < 4; ++j) {
        int c = w * 4 + j;
        int rloc = (c & 7) * 16 + (lane >> 2);
        int koff = (lane & 3) * 8;
        if (c < 8) {
            int gr = bm0 + rloc;
            if (gr > M - 1) gr = M - 1;
            if (AMAP == 1) gr = (gr >> 3) * 16 + 8 + (gr & 7);
            if (AMAP == 2) gr = (gr >> 2) * 16 + 12 + (gr & 3);
            gsrc[j] = A + (size_t)gr * K + koff;
            ldst[j] = Al + c * 512;
        } else {
            int gn = bn0 + rloc;  // N is a multiple of 128 for all our GEMMs
            gsrc[j] = Bt + (size_t)gn * K + koff;
            ldst[j] = Bl + (c - 8) * 512;
        }
    }

    const int wm = (w & 1) * 64;
    const int wn = (w >> 1) * 64;
    const int fr = lane & 15;
    const int fq = lane >> 4;
    const BF16* alds[4];
    const BF16* blds[4];
#pragma unroll
    for (int t = 0; t < 4; ++t) {
        alds[t] = Al + (wm + t * 16 + fr) * 32 + fq * 8;
        blds[t] = Bl + (wn + t * 16 + fr) * 32 + fq * 8;
    }

    floatx4 acc[4][4];
#pragma unroll
    for (int i = 0; i < 4; ++i)
#pragma unroll
        for (int j = 0; j < 4; ++j) acc[i][j] = (floatx4){0.f, 0.f, 0.f, 0.f};

    for (int k0 = 0; k0 < K; k0 += 32) {
#pragma unroll
        for (int j = 0; j < 4; ++j) {
            __builtin_amdgcn_global_load_lds((gas_cvp)gsrc[j], (las_vp)ldst[j], 16, 0, 0);
            gsrc[j] += 32;
        }
        __syncthreads();
        short8 af[4], bfr[4];
#pragma unroll
        for (int t = 0; t < 4; ++t) {
            af[t] = *(const short8*)alds[t];
            bfr[t] = *(const short8*)blds[t];
        }
#pragma unroll
        for (int mt = 0; mt < 4; ++mt)
#pragma unroll
            for (int nt = 0; nt < 4; ++nt)
                acc[mt][nt] = __builtin_amdgcn_mfma_f32_16x16x32_bf16(af[mt], bfr[nt], acc[mt][nt], 0, 0, 0);
        __syncthreads();
    }

#pragma unroll
    for (int mt = 0; mt < 4; ++mt) {
#pragma unroll
        for (int nt = 0; nt < 4; ++nt) {
            const int gcol = bn0 + wn + nt * 16 + fr;
#pragma unroll
            for (int r = 0; r < 4; ++r) {
                const int grow = bm0 + wm + mt * 16 + fq * 4 + r;
                if (grow < M) {
                    float v = acc[mt][nt][r];
                    if (OMODE != 0) v += bias[gcol];
                    if (OMODE == 0 || OMODE == 1) {
                        ((BF16*)Cout)[(size_t)grow * N + gcol] = f2bf(v);
                    } else if (OMODE == 2) {
                        int t8 = grow & 7;
                        int rr = (grow >> 3) * 16 + 8 + t8;
                        float w8 = (t8 < 4) ? 0.5f : 0.25f;
                        BF16* R = (BF16*)Cout;
                        size_t o = (size_t)rr * 768 + gcol;
                        R[o] = f2bf(0.5f * bf2f(R[o]) + w8 * v);
                    } else if (OMODE == 3) {
                        int t4 = grow & 3;
                        int rr = (grow >> 2) * 16 + 12 + t4;
                        BF16* R = (BF16*)Cout;
                        size_t o = (size_t)rr * 768 + gcol;
                        R[o] = f2bf(bf2f(R[o]) + 0.25f * v);
                    } else if (OMODE == 4) {
                        int b = grow / 3136;
                        int xrow = b * 3137 + 1 + (grow - b * 3136);
                        ((float*)Cout)[(size_t)grow * N + gcol] =
                            v + ((const float*)res)[(size_t)xrow * 768 + gcol];
                    } else if (OMODE == 6) {
                        v = 0.5f * v * (1.0f + erff(v * 0.70710678118654752f));
                        ((BF16*)Cout)[(size_t)grow * N + gcol] = f2bf(v);
                    } else {  // 7
                        v += ((const float*)res)[(size_t)grow * N + gcol];
                        ((float*)Cout)[(size_t)grow * N + gcol] = v;
                    }
                }
            }
        }
    }
}

// ---------------------------------------------------------------------------
// Temporal attention, one block per (group, head). L in {4,8,16}, d=64.
// ---------------------------------------------------------------------------
template <int L, int NT>
__global__ __launch_bounds__(NT) void temporal_attn(const BF16* __restrict__ qkv,
                                                    BF16* __restrict__ outp) {
    __shared__ float q[L * 64];
    __shared__ float k[L * 65];
    __shared__ float v[L * 64];
    __shared__ float S[L * L];
    const int bh = blockIdx.x;
    const int b = bh / 12, h = bh % 12;
    const int tid = threadIdx.x;
    const size_t rb = (size_t)b * L;
    for (int idx = tid; idx < L * 64; idx += NT) {
        int i = idx >> 6, d = idx & 63;
        size_t base = (rb + i) * 2304 + h * 64 + d;
        q[i * 64 + d] = bf2f(qkv[base]);
        k[i * 65 + d] = bf2f(qkv[base + 768]);
        v[i * 64 + d] = bf2f(qkv[base + 1536]);
    }
    __syncthreads();
    for (int idx = tid; idx < L * L; idx += NT) {
        int i = idx / L, j = idx % L;
        float a = 0.f;
#pragma unroll
        for (int d = 0; d < 64; ++d) a += q[i * 64 + d] * k[j * 65 + d];
        S[idx] = a * 0.125f;
    }
    __syncthreads();
    if (tid < L) {
        float mx = -1e30f;
        for (int j = 0; j < L; ++j) mx = fmaxf(mx, S[tid * L + j]);
        float sm = 0.f;
        for (int j = 0; j < L; ++j) { float e = __expf(S[tid * L + j] - mx); S[tid * L + j] = e; sm += e; }
        float inv = 1.0f / sm;
        for (int j = 0; j < L; ++j) S[tid * L + j] *= inv;
    }
    __syncthreads();
    for (int idx = tid; idx < L * 64; idx += NT) {
        int i = idx >> 6, d = idx & 63;
        float acc = 0.f;
#pragma unroll
        for (int j = 0; j < L; ++j) acc += S[i * L + j] * v[j * 64 + d];
        outp[(rb + i) * 768 + h * 64 + d] = f2bf(acc);
    }
}

// ---------------------------------------------------------------------------
// Spatial attention: one block per (bt-group, head), L=197, d=64.
// Pointers are chunk-relative; grid = (#groups in chunk) * 12.
// ---------------------------------------------------------------------------
__global__ __launch_bounds__(256) void spatial_attn(const BF16* __restrict__ qkv,
                                                    BF16* __restrict__ outp) {
    const int bh = blockIdx.x;
    const int bt = bh / 12, h = bh % 12;
    const int rowbase = bt * 197;
    __shared__ BF16 Ks[197 * 66];
    __shared__ BF16 Vs[197 * 66];
    __shared__ float qrow[64];
    __shared__ float P[200];
    __shared__ float red[8];
    __shared__ float pv[4 * 64];
    const int tid = threadIdx.x;
    for (int idx = tid; idx < 197 * 64; idx += 256) {
        int j = idx >> 6, d = idx & 63;
        size_t base = (size_t)(rowbase + j) * 2304 + h * 64 + d;
        Ks[j * 66 + d] = qkv[base + 768];
        Vs[j * 66 + d] = qkv[base + 1536];
    }
    __syncthreads();
    for (int i = 0; i < 197; ++i) {
        if (tid < 64) qrow[tid] = bf2f(qkv[(size_t)(rowbase + i) * 2304 + h * 64 + tid]);
        __syncthreads();
        float sc = -1e30f;
        if (tid < 197) {
            float acc = 0.f;
            const BF16* kr = &Ks[tid * 66];
#pragma unroll
            for (int d = 0; d < 64; ++d) acc += qrow[d] * bf2f(kr[d]);
            sc = acc * 0.125f;
        }
        float mx = sc;
#pragma unroll
        for (int o = 32; o > 0; o >>= 1) mx = fmaxf(mx, __shfl_down(mx, o));
        if ((tid & 63) == 0) red[tid >> 6] = mx;
        __syncthreads();
        mx = fmaxf(fmaxf(red[0], red[1]), fmaxf(red[2], red[3]));
        float pe = (tid < 197) ? __expf(sc - mx) : 0.f;
        float sm = pe;
#pragma unroll
        for (int o = 32; o > 0; o >>= 1) sm += __shfl_down(sm, o);
        if ((tid & 63) == 0) red[4 + (tid >> 6)] = sm;
        __syncthreads();
        sm = red[4] + red[5] + red[6] + red[7];
        if (tid < 197) P[tid] = pe / sm;
        __syncthreads();
        {
            int d = tid & 63, ch = tid >> 6;
            float acc = 0.f;
            for (int j = ch; j < 197; j += 4) acc += P[j] * bf2f(Vs[j * 66 + d]);
            pv[ch * 64 + d] = acc;
        }
        __syncthreads();
        if (tid < 64) {
            float o = pv[tid] + pv[64 + tid] + pv[128 + tid] + pv[192 + tid];
            outp[(size_t)(rowbase + i) * 768 + h * 64 + tid] = f2bf(o);
        }
        __syncthreads();
    }
}

// ---------------------------------------------------------------------------
// cls second attention (tiny): no scale factor per reference
// ---------------------------------------------------------------------------
__global__ __launch_bounds__(256) void cls_attn_kernel(const float* __restrict__ clsln,
                                                       float* __restrict__ clsout) {
    const int b = blockIdx.x;
    const int tid = threadIdx.x;
    __shared__ float dots[16];
    __shared__ float aw[16];
    const int t = tid >> 4, l16 = tid & 15;
    const float* tgt = clsln + (size_t)(b * 16 + 15) * 768;
    const float* row = clsln + (size_t)(b * 16 + t) * 768;
    float p = 0.f;
    for (int c = l16; c < 768; c += 16) p += tgt[c] * row[c];
#pragma unroll
    for (int o = 8; o > 0; o >>= 1) p += __shfl_down(p, o, 16);
    if (l16 == 0) dots[t] = p;
    __syncthreads();
    if (tid == 0) {
        float mx = -1e30f;
        for (int j = 0; j < 16; ++j) mx = fmaxf(mx, dots[j]);
        float s = 0.f;
        for (int j = 0; j < 16; ++j) { aw[j] = __expf(dots[j] - mx); s += aw[j]; }
        float inv = 1.0f / s;
        for (int j = 0; j < 16; ++j) aw[j] *= inv;
    }
    __syncthreads();
    for (int c = tid; c < 768; c += 256) {
        float acc = 0.f;
#pragma unroll
        for (int j = 0; j < 16; ++j) acc += aw[j] * clsln[(size_t)(b * 16 + j) * 768 + c];
        clsout[(size_t)b * 768 + c] = acc;
    }
}

// x_cat = concat([init_cls, xt_full]) + concat([cls_sp, x_s]); res_sp is bf16
__global__ __launch_bounds__(256) void xcat_kernel(const float* __restrict__ x,
                                                   const float* __restrict__ xtfull,
                                                   const BF16* __restrict__ res_sp,
                                                   const float* __restrict__ clsout,
                                                   float* __restrict__ xcat) {
    const int gidx = blockIdx.x;
    const int b = gidx / 3137, j = gidx - b * 3137;
    const int tid = threadIdx.x;
    if (j == 0) {
        const float* xr = x + (size_t)b * 3137 * 768;
        const float* cr = clsout + (size_t)b * 768;
#pragma unroll
        for (int i = 0; i < 3; ++i) {
            int c = tid + i * 256;
            xcat[(size_t)gidx * 768 + c] = xr[c] + cr[c];
        }
    } else {
        const int p = j - 1, k = p >> 4, t = p & 15;
        const BF16* rs = res_sp + (size_t)((b * 16 + t) * 197 + 1 + k) * 768;
        const float* xf = xtfull + (size_t)(b * 3136 + p) * 768;
#pragma unroll
        for (int i = 0; i < 3; ++i) {
            int c = tid + i * 256;
            xcat[(size_t)gidx * 768 + c] = xf[c] + bf2f(rs[c]);
        }
    }
}

// ---------------------------------------------------------------------------
extern "C" void kernel_launch(void* const* d_in, const int* in_sizes, int n_in,
                              void* d_out, int out_size, void* d_ws, size_t ws_size,
                              hipStream_t stream) {
    const float* x       = (const float*)d_in[0];
    const float* ln1_g   = (const float*)d_in[4];
    const float* ln1_b   = (const float*)d_in[5];
    const float* lnt_g   = (const float*)d_in[6];
    const float* lnt_b   = (const float*)d_in[7];
    const float* ln2_g   = (const float*)d_in[8];
    const float* ln2_b   = (const float*)d_in[9];
    const float* lncls_g = (const float*)d_in[10];
    const float* lncls_b = (const float*)d_in[11];
    const float* Wqkv_s  = (const float*)d_in[12];
    const float* Wproj_s = (const float*)d_in[13];
    const float* bproj_s = (const float*)d_in[14];
    const float* Wqkv4   = (const float*)d_in[15];
    const float* Wqkv8   = (const float*)d_in[16];
    const float* Wqkv16  = (const float*)d_in[17];
    const float* Wp4     = (const float*)d_in[18];
    const float* bp4     = (const float*)d_in[19];
    const float* Wp8     = (const float*)d_in[20];
    const float* bp8     = (const float*)d_in[21];
    const float* Wp16    = (const float*)d_in[22];
    const float* bp16    = (const float*)d_in[23];
    const float* Wtfc    = (const float*)d_in[24];
    const float* btfc    = (const float*)d_in[25];
    const float* Wfc1    = (const float*)d_in[26];
    const float* bfc1    = (const float*)d_in[27];
    const float* Wfc2    = (const float*)d_in[28];
    const float* bfc2    = (const float*)d_in[29];
    float* out = (float*)d_out;

    // ---- workspace layout (bytes), lifetime-aliased; peak = 96,694,272 (92.2 MiB)
    const size_t oW0 = 0;               // weight slot 0 (4,718,592)
    const size_t oW1 = 4718592;         // weight slot 1 (4,718,592)
    const size_t oA  = 9437184;         // xtn -> atts -> hln           (19,365,888)
    const size_t oC  = 28803072;        // res_temp ; xcat spans C..B   (19,267,584)
    const size_t oB  = 48070656;        // qkv chunks ; tail of xcat    (29,048,832)
    const size_t oD  = 77119488;        // att -> xsn -> res_sp -> h1   (19,365,888)
    const size_t oCL = 96485376;        // clsln fp32 (196,608)
    const size_t oCO = 96681984;        // clsout fp32 (12,288)
    const size_t NEED = 96694272;
    if (ws_size < NEED) return;
    char* ws = (char*)d_ws;

    BF16* w0       = (BF16*)(ws + oW0);
    BF16* w1       = (BF16*)(ws + oW1);
    BF16* xtn      = (BF16*)(ws + oA);
    BF16* atts     = (BF16*)(ws + oA);
    BF16* hln      = (BF16*)(ws + oA);
    BF16* res_temp = (BF16*)(ws + oC);
    float* xcat    = (float*)(ws + oC);
    BF16* qkv      = (BF16*)(ws + oB);
    BF16* att      = (BF16*)(ws + oD);
    BF16* xsn      = (BF16*)(ws + oD);
    BF16* res_sp   = (BF16*)(ws + oD);
    BF16* h1       = (BF16*)(ws + oD);
    float* clsln   = (float*)(ws + oCL);
    float* clsout  = (float*)(ws + oCO);
    float* xtfull  = out;  // d_out doubles as xtfull fp32 until the final GEMM

    // ---- temporal LN
    ln_kernel<0><<<12544, 256, 0, stream>>>(x, nullptr, nullptr, lnt_g, lnt_b, xtn, nullptr);

    // ---- scale 16 (2 row-chunks of 6272)
    wtrans<<<dim3(24, 72), 256, 0, stream>>>(Wqkv16, w0, 768, 2304);
    for (int c = 0; c < 2; ++c) {
        gemm_bf16<0, 0><<<dim3(49, 18), 256, 0, stream>>>(xtn + (size_t)c * 6272 * 768, w0, nullptr, nullptr, qkv, 6272, 2304, 768);
        temporal_attn<16, 256><<<4704, 256, 0, stream>>>(qkv, att + (size_t)c * 6272 * 768);
    }
    wtrans<<<dim3(24, 24), 256, 0, stream>>>(Wp16, w1, 768, 768);
    gemm_bf16<0, 1><<<dim3(98, 6), 256, 0, stream>>>(att, w1, bp16, nullptr, res_temp, 12544, 768, 768);

    // ---- scale 8 (row-mapped A, merge epilogue)
    wtrans<<<dim3(24, 72), 256, 0, stream>>>(Wqkv8, w0, 768, 2304);
    gemm_bf16<1, 0><<<dim3(49, 18), 256, 0, stream>>>(xtn, w0, nullptr, nullptr, qkv, 6272, 2304, 768);
    temporal_attn<8, 64><<<9408, 64, 0, stream>>>(qkv, att);
    wtrans<<<dim3(24, 24), 256, 0, stream>>>(Wp8, w1, 768, 768);
    gemm_bf16<0, 2><<<dim3(49, 6), 256, 0, stream>>>(att, w1, bp8, nullptr, res_temp, 6272, 768, 768);

    // ---- scale 4
    wtrans<<<dim3(24, 72), 256, 0, stream>>>(Wqkv4, w0, 768, 2304);
    gemm_bf16<2, 0><<<dim3(25, 18), 256, 0, stream>>>(xtn, w0, nullptr, nullptr, qkv, 3136, 2304, 768);
    temporal_attn<4, 64><<<9408, 64, 0, stream>>>(qkv, att);
    wtrans<<<dim3(24, 24), 256, 0, stream>>>(Wp4, w1, 768, 768);
    gemm_bf16<0, 3><<<dim3(25, 6), 256, 0, stream>>>(att, w1, bp4, nullptr, res_temp, 3136, 768, 768);

    // ---- temporal FC + x residual -> xtfull (fp32, in d_out)
    wtrans<<<dim3(24, 24), 256, 0, stream>>>(Wtfc, w0, 768, 768);
    gemm_bf16<0, 4><<<dim3(98, 6), 256, 0, stream>>>(res_temp, w0, btfc, x, xtfull, 12544, 768, 768);

    // ---- spatial path (2 chunks of 32 bt-groups = 6304 rows)
    ln_kernel<1><<<12608, 256, 0, stream>>>(x, xtfull, nullptr, ln1_g, ln1_b, xsn, nullptr);
    wtrans<<<dim3(24, 72), 256, 0, stream>>>(Wqkv_s, w1, 768, 2304);
    for (int c = 0; c < 2; ++c) {
        gemm_bf16<0, 0><<<dim3(50, 18), 256, 0, stream>>>(xsn + (size_t)c * 6304 * 768, w1, nullptr, nullptr, qkv, 6304, 2304, 768);
        spatial_attn<<<384, 256, 0, stream>>>(qkv, atts + (size_t)c * 6304 * 768);
    }
    wtrans<<<dim3(24, 24), 256, 0, stream>>>(Wproj_s, w0, 768, 768);
    gemm_bf16<0, 1><<<dim3(99, 6), 256, 0, stream>>>(atts, w0, bproj_s, nullptr, res_sp, 12608, 768, 768);

    // ---- cls path
    ln_kernel<3><<<64, 256, 0, stream>>>(nullptr, nullptr, res_sp, lncls_g, lncls_b, nullptr, clsln);
    cls_attn_kernel<<<4, 256, 0, stream>>>(clsln, clsout);

    // ---- combine
    xcat_kernel<<<12548, 256, 0, stream>>>(x, xtfull, res_sp, clsout, xcat);
    ln_kernel<2><<<12548, 256, 0, stream>>>(xcat, nullptr, nullptr, ln2_g, ln2_b, hln, nullptr);

    // ---- MLP (4 row-chunks of 3137)
    wtrans<<<dim3(24, 96), 256, 0, stream>>>(Wfc1, w0, 768, 3072);
    wtrans<<<dim3(96, 24), 256, 0, stream>>>(Wfc2, w1, 3072, 768);
    for (int c = 0; c < 4; ++c) {
        gemm_bf16<0, 6><<<dim3(25, 24), 256, 0, stream>>>(hln + (size_t)c * 3137 * 768, w0, bfc1, nullptr, h1, 3137, 3072, 768);
        gemm_bf16<0, 7><<<dim3(25, 6), 256, 0, stream>>>(h1, w1, bfc2, xcat + (size_t)c * 3137 * 768, out + (size_t)c * 3137 * 768, 3137, 768, 3072);
    }
}

// Round 3
// 1410.609 us; speedup vs baseline: 2.0557x; 2.0557x over previous
//
#include <hip/hip_runtime.h>
#include <hip/hip_bf16.h>
#include <stdint.h>

#define BF16 __hip_bfloat16

typedef __attribute__((ext_vector_type(8))) short short8;
typedef __attribute__((ext_vector_type(2))) short short2v;
typedef __attribute__((ext_vector_type(4))) float floatx4;

typedef const __attribute__((address_space(1))) void* gas_cvp;
typedef __attribute__((address_space(3))) void* las_vp;

__device__ __forceinline__ float bf2f(BF16 v) { return __bfloat162float(v); }
__device__ __forceinline__ BF16 f2bf(float v) { return __float2bfloat16(v); }

// ---------------------------------------------------------------------------
// Weight fp32 [K,N] -> bf16 transposed [N,K]
// ---------------------------------------------------------------------------
__global__ __launch_bounds__(256) void wtrans(const float* __restrict__ W,
                                              BF16* __restrict__ Wt, int K, int N) {
    __shared__ float t[32][33];
    int k0 = blockIdx.x * 32, n0 = blockIdx.y * 32;
    int tx = threadIdx.x & 31, ty = threadIdx.x >> 5;  // ty 0..7
#pragma unroll
    for (int i = 0; i < 32; i += 8) t[ty + i][tx] = W[(size_t)(k0 + ty + i) * N + n0 + tx];
    __syncthreads();
#pragma unroll
    for (int i = 0; i < 32; i += 8)
        Wt[(size_t)(n0 + ty + i) * K + k0 + tx] = f2bf(t[tx][ty + i]);
}

// ---------------------------------------------------------------------------
// LayerNorm over 768 cols, block=256.
// MODE 0: rows of x[:,1:,:]  -> bf16
// MODE 1: spatial xs rows (cls from x / patch from xtfull fp32) -> bf16
// MODE 2: plain fp32 rows -> bf16
// MODE 3: cls rows (row*197) of bf16 src -> fp32
// ---------------------------------------------------------------------------
template <int MODE>
__global__ __launch_bounds__(256) void ln_kernel(const float* __restrict__ src0,
                                                 const float* __restrict__ src1,
                                                 const BF16* __restrict__ srcb,
                                                 const float* __restrict__ g,
                                                 const float* __restrict__ bta,
                                                 BF16* __restrict__ dst_bf,
                                                 float* __restrict__ dst_f) {
    const int r = blockIdx.x, tid = threadIdx.x;
    float x0, x1, x2;
    if (MODE == 3) {
        const BF16* src = srcb + (size_t)r * 197 * 768;
        x0 = bf2f(src[tid]); x1 = bf2f(src[tid + 256]); x2 = bf2f(src[tid + 512]);
    } else {
        const float* src;
        if (MODE == 0) {
            int b = r / 3136, rr = r - b * 3136;
            src = src0 + ((size_t)b * 3137 + 1 + rr) * 768;
        } else if (MODE == 1) {
            int bt = r / 197, j = r - bt * 197;
            int b = bt >> 4, t = bt & 15;
            if (j == 0) src = src0 + (size_t)b * 3137 * 768;
            else        src = src1 + ((size_t)b * 3136 + (size_t)(j - 1) * 16 + t) * 768;
        } else {
            src = src0 + (size_t)r * 768;
        }
        x0 = src[tid]; x1 = src[tid + 256]; x2 = src[tid + 512];
    }
    float s = x0 + x1 + x2;
    float ss = x0 * x0 + x1 * x1 + x2 * x2;
    __shared__ float red[8];
#pragma unroll
    for (int o = 32; o > 0; o >>= 1) { s += __shfl_down(s, o); ss += __shfl_down(ss, o); }
    if ((tid & 63) == 0) { red[tid >> 6] = s; red[4 + (tid >> 6)] = ss; }
    __syncthreads();
    s = red[0] + red[1] + red[2] + red[3];
    ss = red[4] + red[5] + red[6] + red[7];
    const float mu = s * (1.0f / 768.0f);
    const float var = ss * (1.0f / 768.0f) - mu * mu;
    const float rstd = rsqrtf(var + 1e-5f);
#pragma unroll
    for (int i = 0; i < 3; ++i) {
        int c = tid + i * 256;
        float xv = (i == 0) ? x0 : (i == 1) ? x1 : x2;
        float y = (xv - mu) * rstd * g[c] + bta[c];
        if (MODE == 3) dst_f[(size_t)r * 768 + c] = y;
        else           dst_bf[(size_t)r * 768 + c] = f2bf(y);
    }
}

// ---------------------------------------------------------------------------
// bf16 GEMM: C[M,N] = A'[M,K] @ Bt[N,K]^T with row-mapped A and fused epilogue.
// AMAP: 0 identity; 1 scale8; 2 scale4
// OMODE: 0 bf16 plain; 1 bf16 +bias; 2 merge8 RMW; 3 merge4 RMW;
//        4 fp32 +bias +x-residual(CLS-skip rows); 6 bf16 +bias+gelu; 7 fp32 +bias+res
// ---------------------------------------------------------------------------
template <int AMAP, int OMODE>
__global__ __launch_bounds__(256) void gemm_bf16(const BF16* __restrict__ A,
                                                 const BF16* __restrict__ Bt,
                                                 const float* __restrict__ bias,
                                                 const void* __restrict__ res,
                                                 void* __restrict__ Cout,
                                                 int M, int N, int K) {
    __shared__ BF16 Al[128 * 32];
    __shared__ BF16 Bl[128 * 32];
    const int tid = threadIdx.x;
    const int lane = tid & 63;
    const int w = tid >> 6;
    const int bm0 = blockIdx.x * 128;
    const int bn0 = blockIdx.y * 128;

    const BF16* gsrc[4];
    BF16* ldst[4];
#pragma unroll
    for (int j = 0; j < 4; ++j) {
        int c = w * 4 + j;
        int rloc = (c & 7) * 16 + (lane >> 2);
        int koff = (lane & 3) * 8;
        if (c < 8) {
            int gr = bm0 + rloc;
            if (gr > M - 1) gr = M - 1;
            if (AMAP == 1) gr = (gr >> 3) * 16 + 8 + (gr & 7);
            if (AMAP == 2) gr = (gr >> 2) * 16 + 12 + (gr & 3);
            gsrc[j] = A + (size_t)gr * K + koff;
            ldst[j] = Al + c * 512;
        } else {
            int gn = bn0 + rloc;
            gsrc[j] = Bt + (size_t)gn * K + koff;
            ldst[j] = Bl + (c - 8) * 512;
        }
    }

    const int wm = (w & 1) * 64;
    const int wn = (w >> 1) * 64;
    const int fr = lane & 15;
    const int fq = lane >> 4;
    const BF16* alds[4];
    const BF16* blds[4];
#pragma unroll
    for (int t = 0; t < 4; ++t) {
        alds[t] = Al + (wm + t * 16 + fr) * 32 + fq * 8;
        blds[t] = Bl + (wn + t * 16 + fr) * 32 + fq * 8;
    }

    floatx4 acc[4][4];
#pragma unroll
    for (int i = 0; i < 4; ++i)
#pragma unroll
        for (int j = 0; j < 4; ++j) acc[i][j] = (floatx4){0.f, 0.f, 0.f, 0.f};

    for (int k0 = 0; k0 < K; k0 += 32) {
#pragma unroll
        for (int j = 0; j < 4; ++j) {
            __builtin_amdgcn_global_load_lds((gas_cvp)gsrc[j], (las_vp)ldst[j], 16, 0, 0);
            gsrc[j] += 32;
        }
        __syncthreads();
        short8 af[4], bfr[4];
#pragma unroll
        for (int t = 0; t < 4; ++t) {
            af[t] = *(const short8*)alds[t];
            bfr[t] = *(const short8*)blds[t];
        }
#pragma unroll
        for (int mt = 0; mt < 4; ++mt)
#pragma unroll
            for (int nt = 0; nt < 4; ++nt)
                acc[mt][nt] = __builtin_amdgcn_mfma_f32_16x16x32_bf16(af[mt], bfr[nt], acc[mt][nt], 0, 0, 0);
        __syncthreads();
    }

#pragma unroll
    for (int mt = 0; mt < 4; ++mt) {
#pragma unroll
        for (int nt = 0; nt < 4; ++nt) {
            const int gcol = bn0 + wn + nt * 16 + fr;
#pragma unroll
            for (int r = 0; r < 4; ++r) {
                const int grow = bm0 + wm + mt * 16 + fq * 4 + r;
                if (grow < M) {
                    float v = acc[mt][nt][r];
                    if (OMODE != 0) v += bias[gcol];
                    if (OMODE == 0 || OMODE == 1) {
                        ((BF16*)Cout)[(size_t)grow * N + gcol] = f2bf(v);
                    } else if (OMODE == 2) {
                        int t8 = grow & 7;
                        int rr = (grow >> 3) * 16 + 8 + t8;
                        float w8 = (t8 < 4) ? 0.5f : 0.25f;
                        BF16* R = (BF16*)Cout;
                        size_t o = (size_t)rr * 768 + gcol;
                        R[o] = f2bf(0.5f * bf2f(R[o]) + w8 * v);
                    } else if (OMODE == 3) {
                        int t4 = grow & 3;
                        int rr = (grow >> 2) * 16 + 12 + t4;
                        BF16* R = (BF16*)Cout;
                        size_t o = (size_t)rr * 768 + gcol;
                        R[o] = f2bf(bf2f(R[o]) + 0.25f * v);
                    } else if (OMODE == 4) {
                        int b = grow / 3136;
                        int xrow = b * 3137 + 1 + (grow - b * 3136);
                        ((float*)Cout)[(size_t)grow * N + gcol] =
                            v + ((const float*)res)[(size_t)xrow * 768 + gcol];
                    } else if (OMODE == 6) {
                        v = 0.5f * v * (1.0f + erff(v * 0.70710678118654752f));
                        ((BF16*)Cout)[(size_t)grow * N + gcol] = f2bf(v);
                    } else {  // 7
                        v += ((const float*)res)[(size_t)grow * N + gcol];
                        ((float*)Cout)[(size_t)grow * N + gcol] = v;
                    }
                }
            }
        }
    }
}

// ---------------------------------------------------------------------------
// Temporal attention, one block per (group, head). L in {4,8,16}, d=64.
// ---------------------------------------------------------------------------
template <int L, int NT>
__global__ __launch_bounds__(NT) void temporal_attn(const BF16* __restrict__ qkv,
                                                    BF16* __restrict__ outp) {
    __shared__ float q[L * 64];
    __shared__ float k[L * 65];
    __shared__ float v[L * 64];
    __shared__ float S[L * L];
    const int bh = blockIdx.x;
    const int b = bh / 12, h = bh % 12;
    const int tid = threadIdx.x;
    const size_t rb = (size_t)b * L;
    for (int idx = tid; idx < L * 64; idx += NT) {
        int i = idx >> 6, d = idx & 63;
        size_t base = (rb + i) * 2304 + h * 64 + d;
        q[i * 64 + d] = bf2f(qkv[base]);
        k[i * 65 + d] = bf2f(qkv[base + 768]);
        v[i * 64 + d] = bf2f(qkv[base + 1536]);
    }
    __syncthreads();
    for (int idx = tid; idx < L * L; idx += NT) {
        int i = idx / L, j = idx % L;
        float a = 0.f;
#pragma unroll
        for (int d = 0; d < 64; ++d) a += q[i * 64 + d] * k[j * 65 + d];
        S[idx] = a * 0.125f;
    }
    __syncthreads();
    if (tid < L) {
        float mx = -1e30f;
        for (int j = 0; j < L; ++j) mx = fmaxf(mx, S[tid * L + j]);
        float sm = 0.f;
        for (int j = 0; j < L; ++j) { float e = __expf(S[tid * L + j] - mx); S[tid * L + j] = e; sm += e; }
        float inv = 1.0f / sm;
        for (int j = 0; j < L; ++j) S[tid * L + j] *= inv;
    }
    __syncthreads();
    for (int idx = tid; idx < L * 64; idx += NT) {
        int i = idx >> 6, d = idx & 63;
        float acc = 0.f;
#pragma unroll
        for (int j = 0; j < L; ++j) acc += S[i * L + j] * v[j * 64 + d];
        outp[(rb + i) * 768 + h * 64 + d] = f2bf(acc);
    }
}

// ---------------------------------------------------------------------------
// MFMA spatial attention. Block = (bt, h, qtile-of-64); 4 waves x 16 queries.
// K in LDS [key][dim] (stride 72); V transposed [dim][key] (stride 232);
// full-S single-pass softmax; P via per-wave LDS for C->A layout transform.
// ---------------------------------------------------------------------------
__global__ __launch_bounds__(256) void spatial_attn_mfma(const BF16* __restrict__ qkv,
                                                         BF16* __restrict__ outp) {
    const int bid = blockIdx.x;
    const int qt = bid & 3;
    const int h = (bid >> 2) % 12;
    const int bt = bid / 48;
    const int rowbase = bt * 197;
    __shared__ BF16 Ks[208 * 72];       // 29952 B
    __shared__ BF16 Vt[64 * 232];       // 29696 B
    __shared__ BF16 Pl[4][16 * 232];    // 29696 B
    const int tid = threadIdx.x;
    const int lane = tid & 63;
    const int w = tid >> 6;
    const int ln = lane & 15;
    const int quad = lane >> 4;

    // ---- stage K rows (keys 0..207, clamped)
    for (int it = tid; it < 208 * 8; it += 256) {
        int key = it >> 3, c = it & 7;
        int kc = key < 197 ? key : 196;
        short8 gk = *(const short8*)(qkv + (size_t)(rowbase + kc) * 2304 + 768 + h * 64 + c * 8);
        *(short8*)&Ks[key * 72 + c * 8] = gk;
    }
    // ---- stage V transposed (keys 0..223 in pairs, clamped)
    for (int it = tid; it < 112 * 8; it += 256) {
        int p = it >> 3, c = it & 7;
        int kc0 = (2 * p < 197) ? 2 * p : 196;
        int kc1 = (2 * p + 1 < 197) ? 2 * p + 1 : 196;
        short8 a = *(const short8*)(qkv + (size_t)(rowbase + kc0) * 2304 + 1536 + h * 64 + c * 8);
        short8 b = *(const short8*)(qkv + (size_t)(rowbase + kc1) * 2304 + 1536 + h * 64 + c * 8);
#pragma unroll
        for (int e = 0; e < 8; ++e) {
            short2v pr;
            pr[0] = a[e];
            pr[1] = b[e];
            *(short2v*)&Vt[(c * 8 + e) * 232 + 2 * p] = pr;
        }
    }
    __syncthreads();

    const int m0 = qt * 64 + w * 16;
    int qrow = m0 + ln; if (qrow > 196) qrow = 196;
    const BF16* qptr = qkv + (size_t)(rowbase + qrow) * 2304 + h * 64 + quad * 8;
    short8 aq0 = *(const short8*)(qptr);
    short8 aq1 = *(const short8*)(qptr + 32);

    // ---- S = Q K^T over 13 key-tiles
    floatx4 sacc[13];
#pragma unroll
    for (int nt = 0; nt < 13; ++nt) sacc[nt] = (floatx4){0.f, 0.f, 0.f, 0.f};
#pragma unroll
    for (int nt = 0; nt < 13; ++nt) {
        const BF16* kb = &Ks[(nt * 16 + ln) * 72 + quad * 8];
        short8 b0 = *(const short8*)kb;
        short8 b1 = *(const short8*)(kb + 32);
        sacc[nt] = __builtin_amdgcn_mfma_f32_16x16x32_bf16(aq0, b0, sacc[nt], 0, 0, 0);
        sacc[nt] = __builtin_amdgcn_mfma_f32_16x16x32_bf16(aq1, b1, sacc[nt], 0, 0, 0);
    }

    // ---- softmax per query row (4 rows/lane; reduce across 16-lane col group)
    const bool kvalid[1] = {};
    (void)kvalid;
#pragma unroll
    for (int r = 0; r < 4; ++r) {
        float mx = -1e30f;
#pragma unroll
        for (int nt = 0; nt < 13; ++nt) {
            float s = sacc[nt][r] * 0.125f;
            sacc[nt][r] = s;
            if (nt * 16 + ln < 197) mx = fmaxf(mx, s);
        }
        mx = fmaxf(mx, __shfl_xor(mx, 1));
        mx = fmaxf(mx, __shfl_xor(mx, 2));
        mx = fmaxf(mx, __shfl_xor(mx, 4));
        mx = fmaxf(mx, __shfl_xor(mx, 8));
        float sum = 0.f;
#pragma unroll
        for (int nt = 0; nt < 13; ++nt) {
            float e = (nt * 16 + ln < 197) ? __expf(sacc[nt][r] - mx) : 0.f;
            sacc[nt][r] = e;
            sum += e;
        }
        sum += __shfl_xor(sum, 1);
        sum += __shfl_xor(sum, 2);
        sum += __shfl_xor(sum, 4);
        sum += __shfl_xor(sum, 8);
        float inv = 1.0f / sum;
#pragma unroll
        for (int nt = 0; nt < 13; ++nt) sacc[nt][r] *= inv;
    }

    // ---- P (C-layout) -> per-wave LDS [query][key]
    BF16* pw = Pl[w];
#pragma unroll
    for (int nt = 0; nt < 13; ++nt)
#pragma unroll
        for (int r = 0; r < 4; ++r)
            pw[(quad * 4 + r) * 232 + nt * 16 + ln] = f2bf(sacc[nt][r]);
#pragma unroll
    for (int r = 0; r < 4; ++r)
        pw[(quad * 4 + r) * 232 + 208 + ln] = f2bf(0.f);

    // ---- O = P V  (7 k-steps x 4 dim-tiles)
    floatx4 oacc[4];
#pragma unroll
    for (int nt = 0; nt < 4; ++nt) oacc[nt] = (floatx4){0.f, 0.f, 0.f, 0.f};
    for (int kb = 0; kb < 7; ++kb) {
        short8 ap = *(const short8*)&pw[ln * 232 + kb * 32 + quad * 8];
#pragma unroll
        for (int nt = 0; nt < 4; ++nt) {
            short8 bv = *(const short8*)&Vt[(nt * 16 + ln) * 232 + kb * 32 + quad * 8];
            oacc[nt] = __builtin_amdgcn_mfma_f32_16x16x32_bf16(ap, bv, oacc[nt], 0, 0, 0);
        }
    }

#pragma unroll
    for (int nt = 0; nt < 4; ++nt) {
        int dim = nt * 16 + ln;
#pragma unroll
        for (int r = 0; r < 4; ++r) {
            int q = m0 + quad * 4 + r;
            if (q < 197)
                outp[(size_t)(rowbase + q) * 768 + h * 64 + dim] = f2bf(oacc[nt][r]);
        }
    }
}

// ---------------------------------------------------------------------------
// cls second attention (tiny)
// ---------------------------------------------------------------------------
__global__ __launch_bounds__(256) void cls_attn_kernel(const float* __restrict__ clsln,
                                                       float* __restrict__ clsout) {
    const int b = blockIdx.x;
    const int tid = threadIdx.x;
    __shared__ float dots[16];
    __shared__ float aw[16];
    const int t = tid >> 4, l16 = tid & 15;
    const float* tgt = clsln + (size_t)(b * 16 + 15) * 768;
    const float* row = clsln + (size_t)(b * 16 + t) * 768;
    float p = 0.f;
    for (int c = l16; c < 768; c += 16) p += tgt[c] * row[c];
#pragma unroll
    for (int o = 8; o > 0; o >>= 1) p += __shfl_down(p, o, 16);
    if (l16 == 0) dots[t] = p;
    __syncthreads();
    if (tid == 0) {
        float mx = -1e30f;
        for (int j = 0; j < 16; ++j) mx = fmaxf(mx, dots[j]);
        float s = 0.f;
        for (int j = 0; j < 16; ++j) { aw[j] = __expf(dots[j] - mx); s += aw[j]; }
        float inv = 1.0f / s;
        for (int j = 0; j < 16; ++j) aw[j] *= inv;
    }
    __syncthreads();
    for (int c = tid; c < 768; c += 256) {
        float acc = 0.f;
#pragma unroll
        for (int j = 0; j < 16; ++j) acc += aw[j] * clsln[(size_t)(b * 16 + j) * 768 + c];
        clsout[(size_t)b * 768 + c] = acc;
    }
}

// x_cat = concat([init_cls, xt_full]) + concat([cls_sp, x_s]); res_sp is bf16
__global__ __launch_bounds__(256) void xcat_kernel(const float* __restrict__ x,
                                                   const float* __restrict__ xtfull,
                                                   const BF16* __restrict__ res_sp,
                                                   const float* __restrict__ clsout,
                                                   float* __restrict__ xcat) {
    const int gidx = blockIdx.x;
    const int b = gidx / 3137, j = gidx - b * 3137;
    const int tid = threadIdx.x;
    if (j == 0) {
        const float* xr = x + (size_t)b * 3137 * 768;
        const float* cr = clsout + (size_t)b * 768;
#pragma unroll
        for (int i = 0; i < 3; ++i) {
            int c = tid + i * 256;
            xcat[(size_t)gidx * 768 + c] = xr[c] + cr[c];
        }
    } else {
        const int p = j - 1, k = p >> 4, t = p & 15;
        const BF16* rs = res_sp + (size_t)((b * 16 + t) * 197 + 1 + k) * 768;
        const float* xf = xtfull + (size_t)(b * 3136 + p) * 768;
#pragma unroll
        for (int i = 0; i < 3; ++i) {
            int c = tid + i * 256;
            xcat[(size_t)gidx * 768 + c] = xf[c] + bf2f(rs[c]);
        }
    }
}

// ---------------------------------------------------------------------------
extern "C" void kernel_launch(void* const* d_in, const int* in_sizes, int n_in,
                              void* d_out, int out_size, void* d_ws, size_t ws_size,
                              hipStream_t stream) {
    const float* x       = (const float*)d_in[0];
    const float* ln1_g   = (const float*)d_in[4];
    const float* ln1_b   = (const float*)d_in[5];
    const float* lnt_g   = (const float*)d_in[6];
    const float* lnt_b   = (const float*)d_in[7];
    const float* ln2_g   = (const float*)d_in[8];
    const float* ln2_b   = (const float*)d_in[9];
    const float* lncls_g = (const float*)d_in[10];
    const float* lncls_b = (const float*)d_in[11];
    const float* Wqkv_s  = (const float*)d_in[12];
    const float* Wproj_s = (const float*)d_in[13];
    const float* bproj_s = (const float*)d_in[14];
    const float* Wqkv4   = (const float*)d_in[15];
    const float* Wqkv8   = (const float*)d_in[16];
    const float* Wqkv16  = (const float*)d_in[17];
    const float* Wp4     = (const float*)d_in[18];
    const float* bp4     = (const float*)d_in[19];
    const float* Wp8     = (const float*)d_in[20];
    const float* bp8     = (const float*)d_in[21];
    const float* Wp16    = (const float*)d_in[22];
    const float* bp16    = (const float*)d_in[23];
    const float* Wtfc    = (const float*)d_in[24];
    const float* btfc    = (const float*)d_in[25];
    const float* Wfc1    = (const float*)d_in[26];
    const float* bfc1    = (const float*)d_in[27];
    const float* Wfc2    = (const float*)d_in[28];
    const float* bfc2    = (const float*)d_in[29];
    float* out = (float*)d_out;

    // ---- workspace layout (bytes), lifetime-aliased; peak = 96,694,272 (92.2 MiB)
    const size_t oW0 = 0;
    const size_t oW1 = 4718592;
    const size_t oA  = 9437184;
    const size_t oC  = 28803072;
    const size_t oB  = 48070656;
    const size_t oD  = 77119488;
    const size_t oCL = 96485376;
    const size_t oCO = 96681984;
    const size_t NEED = 96694272;
    if (ws_size < NEED) return;
    char* ws = (char*)d_ws;

    BF16* w0       = (BF16*)(ws + oW0);
    BF16* w1       = (BF16*)(ws + oW1);
    BF16* xtn      = (BF16*)(ws + oA);
    BF16* atts     = (BF16*)(ws + oA);
    BF16* hln      = (BF16*)(ws + oA);
    BF16* res_temp = (BF16*)(ws + oC);
    float* xcat    = (float*)(ws + oC);
    BF16* qkv      = (BF16*)(ws + oB);
    BF16* att      = (BF16*)(ws + oD);
    BF16* xsn      = (BF16*)(ws + oD);
    BF16* res_sp   = (BF16*)(ws + oD);
    BF16* h1       = (BF16*)(ws + oD);
    float* clsln   = (float*)(ws + oCL);
    float* clsout  = (float*)(ws + oCO);
    float* xtfull  = out;

    // ---- temporal LN
    ln_kernel<0><<<12544, 256, 0, stream>>>(x, nullptr, nullptr, lnt_g, lnt_b, xtn, nullptr);

    // ---- scale 16 (2 row-chunks of 6272)
    wtrans<<<dim3(24, 72), 256, 0, stream>>>(Wqkv16, w0, 768, 2304);
    for (int c = 0; c < 2; ++c) {
        gemm_bf16<0, 0><<<dim3(49, 18), 256, 0, stream>>>(xtn + (size_t)c * 6272 * 768, w0, nullptr, nullptr, qkv, 6272, 2304, 768);
        temporal_attn<16, 256><<<4704, 256, 0, stream>>>(qkv, att + (size_t)c * 6272 * 768);
    }
    wtrans<<<dim3(24, 24), 256, 0, stream>>>(Wp16, w1, 768, 768);
    gemm_bf16<0, 1><<<dim3(98, 6), 256, 0, stream>>>(att, w1, bp16, nullptr, res_temp, 12544, 768, 768);

    // ---- scale 8
    wtrans<<<dim3(24, 72), 256, 0, stream>>>(Wqkv8, w0, 768, 2304);
    gemm_bf16<1, 0><<<dim3(49, 18), 256, 0, stream>>>(xtn, w0, nullptr, nullptr, qkv, 6272, 2304, 768);
    temporal_attn<8, 64><<<9408, 64, 0, stream>>>(qkv, att);
    wtrans<<<dim3(24, 24), 256, 0, stream>>>(Wp8, w1, 768, 768);
    gemm_bf16<0, 2><<<dim3(49, 6), 256, 0, stream>>>(att, w1, bp8, nullptr, res_temp, 6272, 768, 768);

    // ---- scale 4
    wtrans<<<dim3(24, 72), 256, 0, stream>>>(Wqkv4, w0, 768, 2304);
    gemm_bf16<2, 0><<<dim3(25, 18), 256, 0, stream>>>(xtn, w0, nullptr, nullptr, qkv, 3136, 2304, 768);
    temporal_attn<4, 64><<<9408, 64, 0, stream>>>(qkv, att);
    wtrans<<<dim3(24, 24), 256, 0, stream>>>(Wp4, w1, 768, 768);
    gemm_bf16<0, 3><<<dim3(25, 6), 256, 0, stream>>>(att, w1, bp4, nullptr, res_temp, 3136, 768, 768);

    // ---- temporal FC + x residual -> xtfull (fp32, in d_out)
    wtrans<<<dim3(24, 24), 256, 0, stream>>>(Wtfc, w0, 768, 768);
    gemm_bf16<0, 4><<<dim3(98, 6), 256, 0, stream>>>(res_temp, w0, btfc, x, xtfull, 12544, 768, 768);

    // ---- spatial path (2 chunks of 32 bt-groups = 6304 rows)
    ln_kernel<1><<<12608, 256, 0, stream>>>(x, xtfull, nullptr, ln1_g, ln1_b, xsn, nullptr);
    wtrans<<<dim3(24, 72), 256, 0, stream>>>(Wqkv_s, w1, 768, 2304);
    for (int c = 0; c < 2; ++c) {
        gemm_bf16<0, 0><<<dim3(50, 18), 256, 0, stream>>>(xsn + (size_t)c * 6304 * 768, w1, nullptr, nullptr, qkv, 6304, 2304, 768);
        spatial_attn_mfma<<<1536, 256, 0, stream>>>(qkv, atts + (size_t)c * 6304 * 768);
    }
    wtrans<<<dim3(24, 24), 256, 0, stream>>>(Wproj_s, w0, 768, 768);
    gemm_bf16<0, 1><<<dim3(99, 6), 256, 0, stream>>>(atts, w0, bproj_s, nullptr, res_sp, 12608, 768, 768);

    // ---- cls path
    ln_kernel<3><<<64, 256, 0, stream>>>(nullptr, nullptr, res_sp, lncls_g, lncls_b, nullptr, clsln);
    cls_attn_kernel<<<4, 256, 0, stream>>>(clsln, clsout);

    // ---- combine
    xcat_kernel<<<12548, 256, 0, stream>>>(x, xtfull, res_sp, clsout, xcat);
    ln_kernel<2><<<12548, 256, 0, stream>>>(xcat, nullptr, nullptr, ln2_g, ln2_b, hln, nullptr);

    // ---- MLP (4 row-chunks of 3137)
    wtrans<<<dim3(24, 96), 256, 0, stream>>>(Wfc1, w0, 768, 3072);
    wtrans<<<dim3(96, 24), 256, 0, stream>>>(Wfc2, w1, 3072, 768);
    for (int c = 0; c < 4; ++c) {
        gemm_bf16<0, 6><<<dim3(25, 24), 256, 0, stream>>>(hln + (size_t)c * 3137 * 768, w0, bfc1, nullptr, h1, 3137, 3072, 768);
        gemm_bf16<0, 7><<<dim3(25, 6), 256, 0, stream>>>(h1, w1, bfc2, xcat + (size_t)c * 3137 * 768, out + (size_t)c * 3137 * 768, 3137, 768, 3072);
    }
}

// Round 4
// 1208.989 us; speedup vs baseline: 2.3985x; 1.1668x over previous
//
#include <hip/hip_runtime.h>
#include <hip/hip_bf16.h>
#include <stdint.h>

#define BF16 __hip_bfloat16

typedef __attribute__((ext_vector_type(8))) short short8;
typedef __attribute__((ext_vector_type(2))) short short2v;
typedef __attribute__((ext_vector_type(4))) float floatx4;

typedef const __attribute__((address_space(1))) void* gas_cvp;
typedef __attribute__((address_space(3))) void* las_vp;

__device__ __forceinline__ float bf2f(BF16 v) { return __bfloat162float(v); }
__device__ __forceinline__ BF16 f2bf(float v) { return __float2bfloat16(v); }

// ---------------------------------------------------------------------------
// Weight fp32 [K,N] -> bf16 transposed [N,K]
// ---------------------------------------------------------------------------
__global__ __launch_bounds__(256) void wtrans(const float* __restrict__ W,
                                              BF16* __restrict__ Wt, int K, int N) {
    __shared__ float t[32][33];
    int k0 = blockIdx.x * 32, n0 = blockIdx.y * 32;
    int tx = threadIdx.x & 31, ty = threadIdx.x >> 5;  // ty 0..7
#pragma unroll
    for (int i = 0; i < 32; i += 8) t[ty + i][tx] = W[(size_t)(k0 + ty + i) * N + n0 + tx];
    __syncthreads();
#pragma unroll
    for (int i = 0; i < 32; i += 8)
        Wt[(size_t)(n0 + ty + i) * K + k0 + tx] = f2bf(t[tx][ty + i]);
}

// ---------------------------------------------------------------------------
// LayerNorm over 768 cols, block=256.
// MODE 0: rows of x[:,1:,:]  -> bf16
// MODE 1: spatial xs rows (cls from x fp32 / patch from xtfull-in-dout) -> bf16
// MODE 2: plain fp32 rows -> bf16
// MODE 3: cls rows (row*197) of bf16 src -> fp32
// ---------------------------------------------------------------------------
template <int MODE>
__global__ __launch_bounds__(256) void ln_kernel(const float* __restrict__ src0,
                                                 const float* __restrict__ src1,
                                                 const BF16* __restrict__ srcb,
                                                 const float* __restrict__ g,
                                                 const float* __restrict__ bta,
                                                 BF16* __restrict__ dst_bf,
                                                 float* __restrict__ dst_f) {
    const int r = blockIdx.x, tid = threadIdx.x;
    float x0, x1, x2;
    if (MODE == 3) {
        const BF16* src = srcb + (size_t)r * 197 * 768;
        x0 = bf2f(src[tid]); x1 = bf2f(src[tid + 256]); x2 = bf2f(src[tid + 512]);
    } else {
        const float* src;
        if (MODE == 0) {
            int b = r / 3136, rr = r - b * 3136;
            src = src0 + ((size_t)b * 3137 + 1 + rr) * 768;
        } else if (MODE == 1) {
            int bt = r / 197, j = r - bt * 197;
            int b = bt >> 4, t = bt & 15;
            if (j == 0) src = src0 + (size_t)b * 3137 * 768;
            else        src = src1 + ((size_t)(b * 3137 + 1) + (size_t)(j - 1) * 16 + t) * 768;
        } else {
            src = src0 + (size_t)r * 768;
        }
        x0 = src[tid]; x1 = src[tid + 256]; x2 = src[tid + 512];
    }
    float s = x0 + x1 + x2;
    float ss = x0 * x0 + x1 * x1 + x2 * x2;
    __shared__ float red[8];
#pragma unroll
    for (int o = 32; o > 0; o >>= 1) { s += __shfl_down(s, o); ss += __shfl_down(ss, o); }
    if ((tid & 63) == 0) { red[tid >> 6] = s; red[4 + (tid >> 6)] = ss; }
    __syncthreads();
    s = red[0] + red[1] + red[2] + red[3];
    ss = red[4] + red[5] + red[6] + red[7];
    const float mu = s * (1.0f / 768.0f);
    const float var = ss * (1.0f / 768.0f) - mu * mu;
    const float rstd = rsqrtf(var + 1e-5f);
#pragma unroll
    for (int i = 0; i < 3; ++i) {
        int c = tid + i * 256;
        float xv = (i == 0) ? x0 : (i == 1) ? x1 : x2;
        float y = (xv - mu) * rstd * g[c] + bta[c];
        if (MODE == 3) dst_f[(size_t)r * 768 + c] = y;
        else           dst_bf[(size_t)r * 768 + c] = f2bf(y);
    }
}

// ---------------------------------------------------------------------------
// bf16 GEMM: C[M,N] = A'[M,K] @ Bt[N,K]^T with row-mapped A and fused epilogue.
// AMAP: 0 identity; 1 scale8; 2 scale4
// OMODE: 0 bf16 plain; 1 bf16 +bias; 2 merge8 RMW; 3 merge4 RMW;
//        4 fp32 +bias +x-residual, written at CLS-skip row (xtfull in d_out);
//        6 bf16 +bias+gelu; 7 fp32 +bias+res(in-place ok); 8 fp32 +res accumulate
// ---------------------------------------------------------------------------
template <int AMAP, int OMODE>
__global__ __launch_bounds__(256) void gemm_bf16(const BF16* __restrict__ A,
                                                 const BF16* __restrict__ Bt,
                                                 const float* __restrict__ bias,
                                                 const void* res,
                                                 void* Cout,
                                                 int M, int N, int K) {
    __shared__ BF16 Al[128 * 32];
    __shared__ BF16 Bl[128 * 32];
    const int tid = threadIdx.x;
    const int lane = tid & 63;
    const int w = tid >> 6;
    const int bm0 = blockIdx.x * 128;
    const int bn0 = blockIdx.y * 128;

    const BF16* gsrc[4];
    BF16* ldst[4];
#pragma unroll
    for (int j = 0; j < 4; ++j) {
        int c = w * 4 + j;
        int rloc = (c & 7) * 16 + (lane >> 2);
        int koff = (lane & 3) * 8;
        if (c < 8) {
            int gr = bm0 + rloc;
            if (gr > M - 1) gr = M - 1;
            if (AMAP == 1) gr = (gr >> 3) * 16 + 8 + (gr & 7);
            if (AMAP == 2) gr = (gr >> 2) * 16 + 12 + (gr & 3);
            gsrc[j] = A + (size_t)gr * K + koff;
            ldst[j] = Al + c * 512;
        } else {
            int gn = bn0 + rloc;
            gsrc[j] = Bt + (size_t)gn * K + koff;
            ldst[j] = Bl + (c - 8) * 512;
        }
    }

    const int wm = (w & 1) * 64;
    const int wn = (w >> 1) * 64;
    const int fr = lane & 15;
    const int fq = lane >> 4;
    const BF16* alds[4];
    const BF16* blds[4];
#pragma unroll
    for (int t = 0; t < 4; ++t) {
        alds[t] = Al + (wm + t * 16 + fr) * 32 + fq * 8;
        blds[t] = Bl + (wn + t * 16 + fr) * 32 + fq * 8;
    }

    floatx4 acc[4][4];
#pragma unroll
    for (int i = 0; i < 4; ++i)
#pragma unroll
        for (int j = 0; j < 4; ++j) acc[i][j] = (floatx4){0.f, 0.f, 0.f, 0.f};

    for (int k0 = 0; k0 < K; k0 += 32) {
#pragma unroll
        for (int j = 0; j < 4; ++j) {
            __builtin_amdgcn_global_load_lds((gas_cvp)gsrc[j], (las_vp)ldst[j], 16, 0, 0);
            gsrc[j] += 32;
        }
        __syncthreads();
        short8 af[4], bfr[4];
#pragma unroll
        for (int t = 0; t < 4; ++t) {
            af[t] = *(const short8*)alds[t];
            bfr[t] = *(const short8*)blds[t];
        }
#pragma unroll
        for (int mt = 0; mt < 4; ++mt)
#pragma unroll
            for (int nt = 0; nt < 4; ++nt)
                acc[mt][nt] = __builtin_amdgcn_mfma_f32_16x16x32_bf16(af[mt], bfr[nt], acc[mt][nt], 0, 0, 0);
        __syncthreads();
    }

#pragma unroll
    for (int mt = 0; mt < 4; ++mt) {
#pragma unroll
        for (int nt = 0; nt < 4; ++nt) {
            const int gcol = bn0 + wn + nt * 16 + fr;
#pragma unroll
            for (int r = 0; r < 4; ++r) {
                const int grow = bm0 + wm + mt * 16 + fq * 4 + r;
                if (grow < M) {
                    float v = acc[mt][nt][r];
                    if (OMODE != 0 && OMODE != 8) v += bias[gcol];
                    if (OMODE == 0 || OMODE == 1) {
                        ((BF16*)Cout)[(size_t)grow * N + gcol] = f2bf(v);
                    } else if (OMODE == 2) {
                        int t8 = grow & 7;
                        int rr = (grow >> 3) * 16 + 8 + t8;
                        float w8 = (t8 < 4) ? 0.5f : 0.25f;
                        BF16* R = (BF16*)Cout;
                        size_t o = (size_t)rr * 768 + gcol;
                        R[o] = f2bf(0.5f * bf2f(R[o]) + w8 * v);
                    } else if (OMODE == 3) {
                        int t4 = grow & 3;
                        int rr = (grow >> 2) * 16 + 12 + t4;
                        BF16* R = (BF16*)Cout;
                        size_t o = (size_t)rr * 768 + gcol;
                        R[o] = f2bf(bf2f(R[o]) + 0.25f * v);
                    } else if (OMODE == 4) {
                        int b = grow / 3136;
                        size_t xrow = (size_t)b * 3137 + 1 + (grow - b * 3136);
                        ((float*)Cout)[xrow * 768 + gcol] =
                            v + ((const float*)res)[xrow * 768 + gcol];
                    } else if (OMODE == 6) {
                        v = 0.5f * v * (1.0f + erff(v * 0.70710678118654752f));
                        ((BF16*)Cout)[(size_t)grow * N + gcol] = f2bf(v);
                    } else {  // 7, 8
                        v += ((const float*)res)[(size_t)grow * N + gcol];
                        ((float*)Cout)[(size_t)grow * N + gcol] = v;
                    }
                }
            }
        }
    }
}

// ---------------------------------------------------------------------------
// Temporal attention, one block per (group, head). L in {4,8,16}, d=64.
// ---------------------------------------------------------------------------
template <int L, int NT>
__global__ __launch_bounds__(NT) void temporal_attn(const BF16* __restrict__ qkv,
                                                    BF16* __restrict__ outp) {
    __shared__ float q[L * 64];
    __shared__ float k[L * 65];
    __shared__ float v[L * 64];
    __shared__ float S[L * L];
    const int bh = blockIdx.x;
    const int b = bh / 12, h = bh % 12;
    const int tid = threadIdx.x;
    const size_t rb = (size_t)b * L;
    for (int idx = tid; idx < L * 64; idx += NT) {
        int i = idx >> 6, d = idx & 63;
        size_t base = (rb + i) * 2304 + h * 64 + d;
        q[i * 64 + d] = bf2f(qkv[base]);
        k[i * 65 + d] = bf2f(qkv[base + 768]);
        v[i * 64 + d] = bf2f(qkv[base + 1536]);
    }
    __syncthreads();
    for (int idx = tid; idx < L * L; idx += NT) {
        int i = idx / L, j = idx % L;
        float a = 0.f;
#pragma unroll
        for (int d = 0; d < 64; ++d) a += q[i * 64 + d] * k[j * 65 + d];
        S[idx] = a * 0.125f;
    }
    __syncthreads();
    if (tid < L) {
        float mx = -1e30f;
        for (int j = 0; j < L; ++j) mx = fmaxf(mx, S[tid * L + j]);
        float sm = 0.f;
        for (int j = 0; j < L; ++j) { float e = __expf(S[tid * L + j] - mx); S[tid * L + j] = e; sm += e; }
        float inv = 1.0f / sm;
        for (int j = 0; j < L; ++j) S[tid * L + j] *= inv;
    }
    __syncthreads();
    for (int idx = tid; idx < L * 64; idx += NT) {
        int i = idx >> 6, d = idx & 63;
        float acc = 0.f;
#pragma unroll
        for (int j = 0; j < L; ++j) acc += S[i * L + j] * v[j * 64 + d];
        outp[(rb + i) * 768 + h * 64 + d] = f2bf(acc);
    }
}

// ---------------------------------------------------------------------------
// MFMA spatial attention. Block = (bt, h, qtile-of-64); 4 waves x 16 queries.
// ---------------------------------------------------------------------------
__global__ __launch_bounds__(256) void spatial_attn_mfma(const BF16* __restrict__ qkv,
                                                         BF16* __restrict__ outp) {
    const int bid = blockIdx.x;
    const int qt = bid & 3;
    const int h = (bid >> 2) % 12;
    const int bt = bid / 48;
    const int rowbase = bt * 197;
    __shared__ BF16 Ks[208 * 72];
    __shared__ BF16 Vt[64 * 232];
    __shared__ BF16 Pl[4][16 * 232];
    const int tid = threadIdx.x;
    const int lane = tid & 63;
    const int w = tid >> 6;
    const int ln = lane & 15;
    const int quad = lane >> 4;

    for (int it = tid; it < 208 * 8; it += 256) {
        int key = it >> 3, c = it & 7;
        int kc = key < 197 ? key : 196;
        short8 gk = *(const short8*)(qkv + (size_t)(rowbase + kc) * 2304 + 768 + h * 64 + c * 8);
        *(short8*)&Ks[key * 72 + c * 8] = gk;
    }
    for (int it = tid; it < 112 * 8; it += 256) {
        int p = it >> 3, c = it & 7;
        int kc0 = (2 * p < 197) ? 2 * p : 196;
        int kc1 = (2 * p + 1 < 197) ? 2 * p + 1 : 196;
        short8 a = *(const short8*)(qkv + (size_t)(rowbase + kc0) * 2304 + 1536 + h * 64 + c * 8);
        short8 b = *(const short8*)(qkv + (size_t)(rowbase + kc1) * 2304 + 1536 + h * 64 + c * 8);
#pragma unroll
        for (int e = 0; e < 8; ++e) {
            short2v pr;
            pr[0] = a[e];
            pr[1] = b[e];
            *(short2v*)&Vt[(c * 8 + e) * 232 + 2 * p] = pr;
        }
    }
    __syncthreads();

    const int m0 = qt * 64 + w * 16;
    int qrow = m0 + ln; if (qrow > 196) qrow = 196;
    const BF16* qptr = qkv + (size_t)(rowbase + qrow) * 2304 + h * 64 + quad * 8;
    short8 aq0 = *(const short8*)(qptr);
    short8 aq1 = *(const short8*)(qptr + 32);

    floatx4 sacc[13];
#pragma unroll
    for (int nt = 0; nt < 13; ++nt) sacc[nt] = (floatx4){0.f, 0.f, 0.f, 0.f};
#pragma unroll
    for (int nt = 0; nt < 13; ++nt) {
        const BF16* kb = &Ks[(nt * 16 + ln) * 72 + quad * 8];
        short8 b0 = *(const short8*)kb;
        short8 b1 = *(const short8*)(kb + 32);
        sacc[nt] = __builtin_amdgcn_mfma_f32_16x16x32_bf16(aq0, b0, sacc[nt], 0, 0, 0);
        sacc[nt] = __builtin_amdgcn_mfma_f32_16x16x32_bf16(aq1, b1, sacc[nt], 0, 0, 0);
    }

#pragma unroll
    for (int r = 0; r < 4; ++r) {
        float mx = -1e30f;
#pragma unroll
        for (int nt = 0; nt < 13; ++nt) {
            float s = sacc[nt][r] * 0.125f;
            sacc[nt][r] = s;
            if (nt * 16 + ln < 197) mx = fmaxf(mx, s);
        }
        mx = fmaxf(mx, __shfl_xor(mx, 1));
        mx = fmaxf(mx, __shfl_xor(mx, 2));
        mx = fmaxf(mx, __shfl_xor(mx, 4));
        mx = fmaxf(mx, __shfl_xor(mx, 8));
        float sum = 0.f;
#pragma unroll
        for (int nt = 0; nt < 13; ++nt) {
            float e = (nt * 16 + ln < 197) ? __expf(sacc[nt][r] - mx) : 0.f;
            sacc[nt][r] = e;
            sum += e;
        }
        sum += __shfl_xor(sum, 1);
        sum += __shfl_xor(sum, 2);
        sum += __shfl_xor(sum, 4);
        sum += __shfl_xor(sum, 8);
        float inv = 1.0f / sum;
#pragma unroll
        for (int nt = 0; nt < 13; ++nt) sacc[nt][r] *= inv;
    }

    BF16* pw = Pl[w];
#pragma unroll
    for (int nt = 0; nt < 13; ++nt)
#pragma unroll
        for (int r = 0; r < 4; ++r)
            pw[(quad * 4 + r) * 232 + nt * 16 + ln] = f2bf(sacc[nt][r]);
#pragma unroll
    for (int r = 0; r < 4; ++r)
        pw[(quad * 4 + r) * 232 + 208 + ln] = f2bf(0.f);

    floatx4 oacc[4];
#pragma unroll
    for (int nt = 0; nt < 4; ++nt) oacc[nt] = (floatx4){0.f, 0.f, 0.f, 0.f};
    for (int kb = 0; kb < 7; ++kb) {
        short8 ap = *(const short8*)&pw[ln * 232 + kb * 32 + quad * 8];
#pragma unroll
        for (int nt = 0; nt < 4; ++nt) {
            short8 bv = *(const short8*)&Vt[(nt * 16 + ln) * 232 + kb * 32 + quad * 8];
            oacc[nt] = __builtin_amdgcn_mfma_f32_16x16x32_bf16(ap, bv, oacc[nt], 0, 0, 0);
        }
    }

#pragma unroll
    for (int nt = 0; nt < 4; ++nt) {
        int dim = nt * 16 + ln;
#pragma unroll
        for (int r = 0; r < 4; ++r) {
            int q = m0 + quad * 4 + r;
            if (q < 197)
                outp[(size_t)(rowbase + q) * 768 + h * 64 + dim] = f2bf(oacc[nt][r]);
        }
    }
}

// ---------------------------------------------------------------------------
// cls second attention (tiny)
// ---------------------------------------------------------------------------
__global__ __launch_bounds__(256) void cls_attn_kernel(const float* __restrict__ clsln,
                                                       float* __restrict__ clsout) {
    const int b = blockIdx.x;
    const int tid = threadIdx.x;
    __shared__ float dots[16];
    __shared__ float aw[16];
    const int t = tid >> 4, l16 = tid & 15;
    const float* tgt = clsln + (size_t)(b * 16 + 15) * 768;
    const float* row = clsln + (size_t)(b * 16 + t) * 768;
    float p = 0.f;
    for (int c = l16; c < 768; c += 16) p += tgt[c] * row[c];
#pragma unroll
    for (int o = 8; o > 0; o >>= 1) p += __shfl_down(p, o, 16);
    if (l16 == 0) dots[t] = p;
    __syncthreads();
    if (tid == 0) {
        float mx = -1e30f;
        for (int j = 0; j < 16; ++j) mx = fmaxf(mx, dots[j]);
        float s = 0.f;
        for (int j = 0; j < 16; ++j) { aw[j] = __expf(dots[j] - mx); s += aw[j]; }
        float inv = 1.0f / s;
        for (int j = 0; j < 16; ++j) aw[j] *= inv;
    }
    __syncthreads();
    for (int c = tid; c < 768; c += 256) {
        float acc = 0.f;
#pragma unroll
        for (int j = 0; j < 16; ++j) acc += aw[j] * clsln[(size_t)(b * 16 + j) * 768 + c];
        clsout[(size_t)b * 768 + c] = acc;
    }
}

// In-place x_cat build in d_out: row j=0 gets x_cls + cls_sp; rows j>=1 get
// (already-present xtfull) + x_s.  res_sp is bf16.
__global__ __launch_bounds__(256) void xcat_kernel(const float* __restrict__ x,
                                                   const BF16* __restrict__ res_sp,
                                                   const float* __restrict__ clsout,
                                                   float* outbuf) {
    const int gidx = blockIdx.x;
    const int b = gidx / 3137, j = gidx - b * 3137;
    const int tid = threadIdx.x;
    if (j == 0) {
        const float* xr = x + (size_t)b * 3137 * 768;
        const float* cr = clsout + (size_t)b * 768;
#pragma unroll
        for (int i = 0; i < 3; ++i) {
            int c = tid + i * 256;
            outbuf[(size_t)gidx * 768 + c] = xr[c] + cr[c];
        }
    } else {
        const int p = j - 1, k = p >> 4, t = p & 15;
        const BF16* rs = res_sp + (size_t)((b * 16 + t) * 197 + 1 + k) * 768;
#pragma unroll
        for (int i = 0; i < 3; ++i) {
            int c = tid + i * 256;
            outbuf[(size_t)gidx * 768 + c] = outbuf[(size_t)gidx * 768 + c] + bf2f(rs[c]);
        }
    }
}

// ---------------------------------------------------------------------------
extern "C" void kernel_launch(void* const* d_in, const int* in_sizes, int n_in,
                              void* d_out, int out_size, void* d_ws, size_t ws_size,
                              hipStream_t stream) {
    const float* x       = (const float*)d_in[0];
    const float* ln1_g   = (const float*)d_in[4];
    const float* ln1_b   = (const float*)d_in[5];
    const float* lnt_g   = (const float*)d_in[6];
    const float* lnt_b   = (const float*)d_in[7];
    const float* ln2_g   = (const float*)d_in[8];
    const float* ln2_b   = (const float*)d_in[9];
    const float* lncls_g = (const float*)d_in[10];
    const float* lncls_b = (const float*)d_in[11];
    const float* Wqkv_s  = (const float*)d_in[12];
    const float* Wproj_s = (const float*)d_in[13];
    const float* bproj_s = (const float*)d_in[14];
    const float* Wqkv4   = (const float*)d_in[15];
    const float* Wqkv8   = (const float*)d_in[16];
    const float* Wqkv16  = (const float*)d_in[17];
    const float* Wp4     = (const float*)d_in[18];
    const float* bp4     = (const float*)d_in[19];
    const float* Wp8     = (const float*)d_in[20];
    const float* bp8     = (const float*)d_in[21];
    const float* Wp16    = (const float*)d_in[22];
    const float* bp16    = (const float*)d_in[23];
    const float* Wtfc    = (const float*)d_in[24];
    const float* btfc    = (const float*)d_in[25];
    const float* Wfc1    = (const float*)d_in[26];
    const float* bfc1    = (const float*)d_in[27];
    const float* Wfc2    = (const float*)d_in[28];
    const float* bfc2    = (const float*)d_in[29];
    float* out = (float*)d_out;

    // ---- workspace layout (bytes), lifetime-aliased; peak = 96,694,272 (known-good)
    const size_t oW0 = 0;               // weight slot 0 (4,718,592)
    const size_t oW1 = 4718592;         // weight slot 1 (4,718,592)
    const size_t oR1 = 9437184;         // xtn -> atts -> hln          (19,365,888)
    const size_t oR2 = 28803072;        // res_temp ; h1 spans R2..R3  (19,267,584)
    const size_t oR3 = 48070656;        // qkv chunks ; h1 tail        (29,048,832)
    const size_t oR4 = 77119488;        // att -> xsn -> res_sp        (19,365,888)
    const size_t oCL = 96485376;        // clsln fp32 (196,608)
    const size_t oCO = 96681984;        // clsout fp32 (12,288)
    const size_t NEED = 96694272;
    if (ws_size < NEED) return;
    char* ws = (char*)d_ws;

    BF16* w0       = (BF16*)(ws + oW0);
    BF16* w1       = (BF16*)(ws + oW1);
    BF16* xtn      = (BF16*)(ws + oR1);
    BF16* atts     = (BF16*)(ws + oR1);
    BF16* hln      = (BF16*)(ws + oR1);
    BF16* res_temp = (BF16*)(ws + oR2);
    BF16* h1       = (BF16*)(ws + oR2);   // 12548x1536 bf16 = 38,547,456 B (spans R2+R3 head)
    BF16* qkv      = (BF16*)(ws + oR3);
    BF16* att      = (BF16*)(ws + oR4);
    BF16* xsn      = (BF16*)(ws + oR4);
    BF16* res_sp   = (BF16*)(ws + oR4);
    float* clsln   = (float*)(ws + oCL);
    float* clsout  = (float*)(ws + oCO);

    // ---- temporal LN
    ln_kernel<0><<<12544, 256, 0, stream>>>(x, nullptr, nullptr, lnt_g, lnt_b, xtn, nullptr);

    // ---- scale 16 (2 row-chunks of 6272)
    wtrans<<<dim3(24, 72), 256, 0, stream>>>(Wqkv16, w0, 768, 2304);
    for (int c = 0; c < 2; ++c) {
        gemm_bf16<0, 0><<<dim3(49, 18), 256, 0, stream>>>(xtn + (size_t)c * 6272 * 768, w0, nullptr, nullptr, qkv, 6272, 2304, 768);
        temporal_attn<16, 256><<<4704, 256, 0, stream>>>(qkv, att + (size_t)c * 6272 * 768);
    }
    wtrans<<<dim3(24, 24), 256, 0, stream>>>(Wp16, w1, 768, 768);
    gemm_bf16<0, 1><<<dim3(98, 6), 256, 0, stream>>>(att, w1, bp16, nullptr, res_temp, 12544, 768, 768);

    // ---- scale 8
    wtrans<<<dim3(24, 72), 256, 0, stream>>>(Wqkv8, w0, 768, 2304);
    gemm_bf16<1, 0><<<dim3(49, 18), 256, 0, stream>>>(xtn, w0, nullptr, nullptr, qkv, 6272, 2304, 768);
    temporal_attn<8, 64><<<9408, 64, 0, stream>>>(qkv, att);
    wtrans<<<dim3(24, 24), 256, 0, stream>>>(Wp8, w1, 768, 768);
    gemm_bf16<0, 2><<<dim3(49, 6), 256, 0, stream>>>(att, w1, bp8, nullptr, res_temp, 6272, 768, 768);

    // ---- scale 4
    wtrans<<<dim3(24, 72), 256, 0, stream>>>(Wqkv4, w0, 768, 2304);
    gemm_bf16<2, 0><<<dim3(25, 18), 256, 0, stream>>>(xtn, w0, nullptr, nullptr, qkv, 3136, 2304, 768);
    temporal_attn<4, 64><<<9408, 64, 0, stream>>>(qkv, att);
    wtrans<<<dim3(24, 24), 256, 0, stream>>>(Wp4, w1, 768, 768);
    gemm_bf16<0, 3><<<dim3(25, 6), 256, 0, stream>>>(att, w1, bp4, nullptr, res_temp, 3136, 768, 768);

    // ---- temporal FC + x residual -> xtfull stored in d_out at x-like rows
    wtrans<<<dim3(24, 24), 256, 0, stream>>>(Wtfc, w0, 768, 768);
    gemm_bf16<0, 4><<<dim3(98, 6), 256, 0, stream>>>(res_temp, w0, btfc, x, out, 12544, 768, 768);

    // ---- spatial path (2 chunks of 32 bt-groups = 6304 rows)
    ln_kernel<1><<<12608, 256, 0, stream>>>(x, out, nullptr, ln1_g, ln1_b, xsn, nullptr);
    wtrans<<<dim3(24, 72), 256, 0, stream>>>(Wqkv_s, w1, 768, 2304);
    for (int c = 0; c < 2; ++c) {
        gemm_bf16<0, 0><<<dim3(50, 18), 256, 0, stream>>>(xsn + (size_t)c * 6304 * 768, w1, nullptr, nullptr, qkv, 6304, 2304, 768);
        spatial_attn_mfma<<<1536, 256, 0, stream>>>(qkv, atts + (size_t)c * 6304 * 768);
    }
    wtrans<<<dim3(24, 24), 256, 0, stream>>>(Wproj_s, w0, 768, 768);
    gemm_bf16<0, 1><<<dim3(99, 6), 256, 0, stream>>>(atts, w0, bproj_s, nullptr, res_sp, 12608, 768, 768);

    // ---- cls path
    ln_kernel<3><<<64, 256, 0, stream>>>(nullptr, nullptr, res_sp, lncls_g, lncls_b, nullptr, clsln);
    cls_attn_kernel<<<4, 256, 0, stream>>>(clsln, clsout);

    // ---- combine (in-place in d_out)
    xcat_kernel<<<12548, 256, 0, stream>>>(x, res_sp, clsout, out);
    ln_kernel<2><<<12548, 256, 0, stream>>>(out, nullptr, nullptr, ln2_g, ln2_b, hln, nullptr);

    // ---- MLP: full-M, hidden split in 2 halves; fc2 accumulates into d_out
    wtrans<<<dim3(24, 96), 256, 0, stream>>>(Wfc1, w0, 768, 3072);          // w0 = Wfc1t [3072,768]
    wtrans<<<dim3(48, 24), 256, 0, stream>>>(Wfc2, w1, 1536, 768);          // w1a [768,1536]
    wtrans<<<dim3(48, 24), 256, 0, stream>>>(Wfc2 + (size_t)1536 * 768, w1 + (size_t)768 * 1536, 1536, 768);  // w1b

    // half a
    gemm_bf16<0, 6><<<dim3(99, 12), 256, 0, stream>>>(hln, w0, bfc1, nullptr, h1, 12548, 1536, 768);
    gemm_bf16<0, 7><<<dim3(99, 6), 256, 0, stream>>>(h1, w1, bfc2, out, out, 12548, 768, 1536);
    // half b
    gemm_bf16<0, 6><<<dim3(99, 12), 256, 0, stream>>>(hln, w0 + (size_t)1536 * 768, bfc1 + 1536, nullptr, h1, 12548, 1536, 768);
    gemm_bf16<0, 8><<<dim3(99, 6), 256, 0, stream>>>(h1, w1 + (size_t)768 * 1536, nullptr, out, out, 12548, 768, 1536);
}

// Round 5
// 1076.011 us; speedup vs baseline: 2.6950x; 1.1236x over previous
//
#include <hip/hip_runtime.h>
#include <hip/hip_bf16.h>
#include <stdint.h>

#define BF16 __hip_bfloat16

typedef __attribute__((ext_vector_type(8))) short short8;
typedef __attribute__((ext_vector_type(2))) short short2v;
typedef __attribute__((ext_vector_type(4))) float floatx4;

typedef const __attribute__((address_space(1))) void* gas_cvp;
typedef __attribute__((address_space(3))) void* las_vp;

__device__ __forceinline__ float bf2f(BF16 v) { return __bfloat162float(v); }
__device__ __forceinline__ BF16 f2bf(float v) { return __float2bfloat16(v); }

// ---------------------------------------------------------------------------
// Weight fp32 [K,N] -> bf16 transposed [N,K]
// ---------------------------------------------------------------------------
__global__ __launch_bounds__(256) void wtrans(const float* __restrict__ W,
                                              BF16* __restrict__ Wt, int K, int N) {
    __shared__ float t[32][33];
    int k0 = blockIdx.x * 32, n0 = blockIdx.y * 32;
    int tx = threadIdx.x & 31, ty = threadIdx.x >> 5;  // ty 0..7
#pragma unroll
    for (int i = 0; i < 32; i += 8) t[ty + i][tx] = W[(size_t)(k0 + ty + i) * N + n0 + tx];
    __syncthreads();
#pragma unroll
    for (int i = 0; i < 32; i += 8)
        Wt[(size_t)(n0 + ty + i) * K + k0 + tx] = f2bf(t[tx][ty + i]);
}

// ---------------------------------------------------------------------------
// LayerNorm over 768 cols, block=256.
// MODE 0: rows of x[:,1:,:]  -> bf16
// MODE 1: spatial xs rows (cls from x fp32 / patch from xtfull-in-dout) -> bf16
// MODE 2: plain fp32 rows -> bf16
// MODE 3: cls rows (row*197) of bf16 src -> fp32
// ---------------------------------------------------------------------------
template <int MODE>
__global__ __launch_bounds__(256) void ln_kernel(const float* __restrict__ src0,
                                                 const float* __restrict__ src1,
                                                 const BF16* __restrict__ srcb,
                                                 const float* __restrict__ g,
                                                 const float* __restrict__ bta,
                                                 BF16* __restrict__ dst_bf,
                                                 float* __restrict__ dst_f) {
    const int r = blockIdx.x, tid = threadIdx.x;
    float x0, x1, x2;
    if (MODE == 3) {
        const BF16* src = srcb + (size_t)r * 197 * 768;
        x0 = bf2f(src[tid]); x1 = bf2f(src[tid + 256]); x2 = bf2f(src[tid + 512]);
    } else {
        const float* src;
        if (MODE == 0) {
            int b = r / 3136, rr = r - b * 3136;
            src = src0 + ((size_t)b * 3137 + 1 + rr) * 768;
        } else if (MODE == 1) {
            int bt = r / 197, j = r - bt * 197;
            int b = bt >> 4, t = bt & 15;
            if (j == 0) src = src0 + (size_t)b * 3137 * 768;
            else        src = src1 + ((size_t)(b * 3137 + 1) + (size_t)(j - 1) * 16 + t) * 768;
        } else {
            src = src0 + (size_t)r * 768;
        }
        x0 = src[tid]; x1 = src[tid + 256]; x2 = src[tid + 512];
    }
    float s = x0 + x1 + x2;
    float ss = x0 * x0 + x1 * x1 + x2 * x2;
    __shared__ float red[8];
#pragma unroll
    for (int o = 32; o > 0; o >>= 1) { s += __shfl_down(s, o); ss += __shfl_down(ss, o); }
    if ((tid & 63) == 0) { red[tid >> 6] = s; red[4 + (tid >> 6)] = ss; }
    __syncthreads();
    s = red[0] + red[1] + red[2] + red[3];
    ss = red[4] + red[5] + red[6] + red[7];
    const float mu = s * (1.0f / 768.0f);
    const float var = ss * (1.0f / 768.0f) - mu * mu;
    const float rstd = rsqrtf(var + 1e-5f);
#pragma unroll
    for (int i = 0; i < 3; ++i) {
        int c = tid + i * 256;
        float xv = (i == 0) ? x0 : (i == 1) ? x1 : x2;
        float y = (xv - mu) * rstd * g[c] + bta[c];
        if (MODE == 3) dst_f[(size_t)r * 768 + c] = y;
        else           dst_bf[(size_t)r * 768 + c] = f2bf(y);
    }
}

// ---------------------------------------------------------------------------
// bf16 GEMM: C[M,N] = A'[M,K] @ Bt[N,K]^T with row-mapped A and fused epilogue.
// BK=64, XOR-swizzled LDS k-blocks (phys = logical ^ (row&7)), grid x=N-tiles.
// AMAP: 0 identity; 1 scale8; 2 scale4
// OMODE: 0 bf16 plain; 1 bf16 +bias; 2 merge8 RMW; 3 merge4 RMW;
//        4 fp32 +bias +x-residual at CLS-skip row; 6 bf16 +bias+gelu;
//        7 fp32 +bias+res(in-place ok); 8 fp32 +res accumulate
// ---------------------------------------------------------------------------
template <int AMAP, int OMODE>
__global__ __launch_bounds__(256) void gemm_bf16(const BF16* __restrict__ A,
                                                 const BF16* __restrict__ Bt,
                                                 const float* __restrict__ bias,
                                                 const void* res,
                                                 void* Cout,
                                                 int M, int N, int K) {
    __shared__ BF16 Al[128 * 64];
    __shared__ BF16 Bl[128 * 64];
    const int tid = threadIdx.x;
    const int lane = tid & 63;
    const int w = tid >> 6;
    const int bn0 = blockIdx.x * 128;   // N-tile fast-varying: concurrent blocks share A
    const int bm0 = blockIdx.y * 128;

    // staging: 32 chunks (16 A + 16 B) of 8 rows x 128 B; wave w owns 8 chunks.
    // lane -> (row-in-chunk, phys k-block); fetch logical block phys^row for swizzle.
    const BF16* gsrc[8];
    BF16* ldst[8];
    const int rin = lane >> 3;
    const int kblk = (lane & 7) ^ rin;
#pragma unroll
    for (int j = 0; j < 8; ++j) {
        int c = w * 8 + j;
        if (c < 16) {
            int gr = bm0 + c * 8 + rin;
            if (gr > M - 1) gr = M - 1;
            if (AMAP == 1) gr = (gr >> 3) * 16 + 8 + (gr & 7);
            if (AMAP == 2) gr = (gr >> 2) * 16 + 12 + (gr & 3);
            gsrc[j] = A + (size_t)gr * K + kblk * 8;
            ldst[j] = Al + c * 512;
        } else {
            int gn = bn0 + (c - 16) * 8 + rin;
            gsrc[j] = Bt + (size_t)gn * K + kblk * 8;
            ldst[j] = Bl + (c - 16) * 512;
        }
    }

    const int wm = (w & 1) * 64;
    const int wn = (w >> 1) * 64;
    const int fr = lane & 15;
    const int fq = lane >> 4;
    const int sw = fr & 7;
    const int o0 = (fq ^ sw) * 8;        // k-half 0: logical block fq
    const int o1 = ((fq + 4) ^ sw) * 8;  // k-half 1: logical block fq+4
    const BF16* pa[4];
    const BF16* pb[4];
#pragma unroll
    for (int t = 0; t < 4; ++t) {
        pa[t] = Al + (wm + t * 16 + fr) * 64;
        pb[t] = Bl + (wn + t * 16 + fr) * 64;
    }

    floatx4 acc[4][4];
#pragma unroll
    for (int i = 0; i < 4; ++i)
#pragma unroll
        for (int j = 0; j < 4; ++j) acc[i][j] = (floatx4){0.f, 0.f, 0.f, 0.f};

    for (int k0 = 0; k0 < K; k0 += 64) {
#pragma unroll
        for (int j = 0; j < 8; ++j) {
            __builtin_amdgcn_global_load_lds((gas_cvp)gsrc[j], (las_vp)ldst[j], 16, 0, 0);
            gsrc[j] += 64;
        }
        __syncthreads();
        {
            short8 af[4], bfr[4];
#pragma unroll
            for (int t = 0; t < 4; ++t) {
                af[t] = *(const short8*)(pa[t] + o0);
                bfr[t] = *(const short8*)(pb[t] + o0);
            }
#pragma unroll
            for (int mt = 0; mt < 4; ++mt)
#pragma unroll
                for (int nt = 0; nt < 4; ++nt)
                    acc[mt][nt] = __builtin_amdgcn_mfma_f32_16x16x32_bf16(af[mt], bfr[nt], acc[mt][nt], 0, 0, 0);
#pragma unroll
            for (int t = 0; t < 4; ++t) {
                af[t] = *(const short8*)(pa[t] + o1);
                bfr[t] = *(const short8*)(pb[t] + o1);
            }
#pragma unroll
            for (int mt = 0; mt < 4; ++mt)
#pragma unroll
                for (int nt = 0; nt < 4; ++nt)
                    acc[mt][nt] = __builtin_amdgcn_mfma_f32_16x16x32_bf16(af[mt], bfr[nt], acc[mt][nt], 0, 0, 0);
        }
        __syncthreads();
    }

#pragma unroll
    for (int mt = 0; mt < 4; ++mt) {
#pragma unroll
        for (int nt = 0; nt < 4; ++nt) {
            const int gcol = bn0 + wn + nt * 16 + fr;
#pragma unroll
            for (int r = 0; r < 4; ++r) {
                const int grow = bm0 + wm + mt * 16 + fq * 4 + r;
                if (grow < M) {
                    float v = acc[mt][nt][r];
                    if (OMODE != 0 && OMODE != 8) v += bias[gcol];
                    if (OMODE == 0 || OMODE == 1) {
                        ((BF16*)Cout)[(size_t)grow * N + gcol] = f2bf(v);
                    } else if (OMODE == 2) {
                        int t8 = grow & 7;
                        int rr = (grow >> 3) * 16 + 8 + t8;
                        float w8 = (t8 < 4) ? 0.5f : 0.25f;
                        BF16* R = (BF16*)Cout;
                        size_t o = (size_t)rr * 768 + gcol;
                        R[o] = f2bf(0.5f * bf2f(R[o]) + w8 * v);
                    } else if (OMODE == 3) {
                        int t4 = grow & 3;
                        int rr = (grow >> 2) * 16 + 12 + t4;
                        BF16* R = (BF16*)Cout;
                        size_t o = (size_t)rr * 768 + gcol;
                        R[o] = f2bf(bf2f(R[o]) + 0.25f * v);
                    } else if (OMODE == 4) {
                        int b = grow / 3136;
                        size_t xrow = (size_t)b * 3137 + 1 + (grow - b * 3136);
                        ((float*)Cout)[xrow * 768 + gcol] =
                            v + ((const float*)res)[xrow * 768 + gcol];
                    } else if (OMODE == 6) {
                        // fast GELU: x*sigmoid(2*0.7978845608*(x+0.044715x^3))
                        float u = v * (0.7978845608f + 0.0356774081f * v * v);
                        v = v / (1.0f + __expf(-2.0f * u));
                        ((BF16*)Cout)[(size_t)grow * N + gcol] = f2bf(v);
                    } else {  // 7, 8
                        v += ((const float*)res)[(size_t)grow * N + gcol];
                        ((float*)Cout)[(size_t)grow * N + gcol] = v;
                    }
                }
            }
        }
    }
}

// ---------------------------------------------------------------------------
// Temporal attention, one block per (group, head). L in {4,8,16}, d=64.
// ---------------------------------------------------------------------------
template <int L, int NT>
__global__ __launch_bounds__(NT) void temporal_attn(const BF16* __restrict__ qkv,
                                                    BF16* __restrict__ outp) {
    __shared__ float q[L * 64];
    __shared__ float k[L * 65];
    __shared__ float v[L * 64];
    __shared__ float S[L * L];
    const int bh = blockIdx.x;
    const int b = bh / 12, h = bh % 12;
    const int tid = threadIdx.x;
    const size_t rb = (size_t)b * L;
    for (int idx = tid; idx < L * 64; idx += NT) {
        int i = idx >> 6, d = idx & 63;
        size_t base = (rb + i) * 2304 + h * 64 + d;
        q[i * 64 + d] = bf2f(qkv[base]);
        k[i * 65 + d] = bf2f(qkv[base + 768]);
        v[i * 64 + d] = bf2f(qkv[base + 1536]);
    }
    __syncthreads();
    for (int idx = tid; idx < L * L; idx += NT) {
        int i = idx / L, j = idx % L;
        float a = 0.f;
#pragma unroll
        for (int d = 0; d < 64; ++d) a += q[i * 64 + d] * k[j * 65 + d];
        S[idx] = a * 0.125f;
    }
    __syncthreads();
    if (tid < L) {
        float mx = -1e30f;
        for (int j = 0; j < L; ++j) mx = fmaxf(mx, S[tid * L + j]);
        float sm = 0.f;
        for (int j = 0; j < L; ++j) { float e = __expf(S[tid * L + j] - mx); S[tid * L + j] = e; sm += e; }
        float inv = 1.0f / sm;
        for (int j = 0; j < L; ++j) S[tid * L + j] *= inv;
    }
    __syncthreads();
    for (int idx = tid; idx < L * 64; idx += NT) {
        int i = idx >> 6, d = idx & 63;
        float acc = 0.f;
#pragma unroll
        for (int j = 0; j < L; ++j) acc += S[i * L + j] * v[j * 64 + d];
        outp[(rb + i) * 768 + h * 64 + d] = f2bf(acc);
    }
}

// ---------------------------------------------------------------------------
// MFMA spatial attention. Block = (bt, h, qtile-of-64); 4 waves x 16 queries.
// ---------------------------------------------------------------------------
__global__ __launch_bounds__(256) void spatial_attn_mfma(const BF16* __restrict__ qkv,
                                                         BF16* __restrict__ outp) {
    const int bid = blockIdx.x;
    const int qt = bid & 3;
    const int h = (bid >> 2) % 12;
    const int bt = bid / 48;
    const int rowbase = bt * 197;
    __shared__ BF16 Ks[208 * 72];
    __shared__ BF16 Vt[64 * 232];
    __shared__ BF16 Pl[4][16 * 232];
    const int tid = threadIdx.x;
    const int lane = tid & 63;
    const int w = tid >> 6;
    const int ln = lane & 15;
    const int quad = lane >> 4;

    for (int it = tid; it < 208 * 8; it += 256) {
        int key = it >> 3, c = it & 7;
        int kc = key < 197 ? key : 196;
        short8 gk = *(const short8*)(qkv + (size_t)(rowbase + kc) * 2304 + 768 + h * 64 + c * 8);
        *(short8*)&Ks[key * 72 + c * 8] = gk;
    }
    for (int it = tid; it < 112 * 8; it += 256) {
        int p = it >> 3, c = it & 7;
        int kc0 = (2 * p < 197) ? 2 * p : 196;
        int kc1 = (2 * p + 1 < 197) ? 2 * p + 1 : 196;
        short8 a = *(const short8*)(qkv + (size_t)(rowbase + kc0) * 2304 + 1536 + h * 64 + c * 8);
        short8 b = *(const short8*)(qkv + (size_t)(rowbase + kc1) * 2304 + 1536 + h * 64 + c * 8);
#pragma unroll
        for (int e = 0; e < 8; ++e) {
            short2v pr;
            pr[0] = a[e];
            pr[1] = b[e];
            *(short2v*)&Vt[(c * 8 + e) * 232 + 2 * p] = pr;
        }
    }
    __syncthreads();

    const int m0 = qt * 64 + w * 16;
    int qrow = m0 + ln; if (qrow > 196) qrow = 196;
    const BF16* qptr = qkv + (size_t)(rowbase + qrow) * 2304 + h * 64 + quad * 8;
    short8 aq0 = *(const short8*)(qptr);
    short8 aq1 = *(const short8*)(qptr + 32);

    floatx4 sacc[13];
#pragma unroll
    for (int nt = 0; nt < 13; ++nt) sacc[nt] = (floatx4){0.f, 0.f, 0.f, 0.f};
#pragma unroll
    for (int nt = 0; nt < 13; ++nt) {
        const BF16* kb = &Ks[(nt * 16 + ln) * 72 + quad * 8];
        short8 b0 = *(const short8*)kb;
        short8 b1 = *(const short8*)(kb + 32);
        sacc[nt] = __builtin_amdgcn_mfma_f32_16x16x32_bf16(aq0, b0, sacc[nt], 0, 0, 0);
        sacc[nt] = __builtin_amdgcn_mfma_f32_16x16x32_bf16(aq1, b1, sacc[nt], 0, 0, 0);
    }

#pragma unroll
    for (int r = 0; r < 4; ++r) {
        float mx = -1e30f;
#pragma unroll
        for (int nt = 0; nt < 13; ++nt) {
            float s = sacc[nt][r] * 0.125f;
            sacc[nt][r] = s;
            if (nt * 16 + ln < 197) mx = fmaxf(mx, s);
        }
        mx = fmaxf(mx, __shfl_xor(mx, 1));
        mx = fmaxf(mx, __shfl_xor(mx, 2));
        mx = fmaxf(mx, __shfl_xor(mx, 4));
        mx = fmaxf(mx, __shfl_xor(mx, 8));
        float sum = 0.f;
#pragma unroll
        for (int nt = 0; nt < 13; ++nt) {
            float e = (nt * 16 + ln < 197) ? __expf(sacc[nt][r] - mx) : 0.f;
            sacc[nt][r] = e;
            sum += e;
        }
        sum += __shfl_xor(sum, 1);
        sum += __shfl_xor(sum, 2);
        sum += __shfl_xor(sum, 4);
        sum += __shfl_xor(sum, 8);
        float inv = 1.0f / sum;
#pragma unroll
        for (int nt = 0; nt < 13; ++nt) sacc[nt][r] *= inv;
    }

    BF16* pw = Pl[w];
#pragma unroll
    for (int nt = 0; nt < 13; ++nt)
#pragma unroll
        for (int r = 0; r < 4; ++r)
            pw[(quad * 4 + r) * 232 + nt * 16 + ln] = f2bf(sacc[nt][r]);
#pragma unroll
    for (int r = 0; r < 4; ++r)
        pw[(quad * 4 + r) * 232 + 208 + ln] = f2bf(0.f);

    floatx4 oacc[4];
#pragma unroll
    for (int nt = 0; nt < 4; ++nt) oacc[nt] = (floatx4){0.f, 0.f, 0.f, 0.f};
    for (int kb = 0; kb < 7; ++kb) {
        short8 ap = *(const short8*)&pw[ln * 232 + kb * 32 + quad * 8];
#pragma unroll
        for (int nt = 0; nt < 4; ++nt) {
            short8 bv = *(const short8*)&Vt[(nt * 16 + ln) * 232 + kb * 32 + quad * 8];
            oacc[nt] = __builtin_amdgcn_mfma_f32_16x16x32_bf16(ap, bv, oacc[nt], 0, 0, 0);
        }
    }

#pragma unroll
    for (int nt = 0; nt < 4; ++nt) {
        int dim = nt * 16 + ln;
#pragma unroll
        for (int r = 0; r < 4; ++r) {
            int q = m0 + quad * 4 + r;
            if (q < 197)
                outp[(size_t)(rowbase + q) * 768 + h * 64 + dim] = f2bf(oacc[nt][r]);
        }
    }
}

// ---------------------------------------------------------------------------
// cls second attention (tiny)
// ---------------------------------------------------------------------------
__global__ __launch_bounds__(256) void cls_attn_kernel(const float* __restrict__ clsln,
                                                       float* __restrict__ clsout) {
    const int b = blockIdx.x;
    const int tid = threadIdx.x;
    __shared__ float dots[16];
    __shared__ float aw[16];
    const int t = tid >> 4, l16 = tid & 15;
    const float* tgt = clsln + (size_t)(b * 16 + 15) * 768;
    const float* row = clsln + (size_t)(b * 16 + t) * 768;
    float p = 0.f;
    for (int c = l16; c < 768; c += 16) p += tgt[c] * row[c];
#pragma unroll
    for (int o = 8; o > 0; o >>= 1) p += __shfl_down(p, o, 16);
    if (l16 == 0) dots[t] = p;
    __syncthreads();
    if (tid == 0) {
        float mx = -1e30f;
        for (int j = 0; j < 16; ++j) mx = fmaxf(mx, dots[j]);
        float s = 0.f;
        for (int j = 0; j < 16; ++j) { aw[j] = __expf(dots[j] - mx); s += aw[j]; }
        float inv = 1.0f / s;
        for (int j = 0; j < 16; ++j) aw[j] *= inv;
    }
    __syncthreads();
    for (int c = tid; c < 768; c += 256) {
        float acc = 0.f;
#pragma unroll
        for (int j = 0; j < 16; ++j) acc += aw[j] * clsln[(size_t)(b * 16 + j) * 768 + c];
        clsout[(size_t)b * 768 + c] = acc;
    }
}

// In-place x_cat build in d_out: row j=0 gets x_cls + cls_sp; rows j>=1 get
// (already-present xtfull) + x_s.  res_sp is bf16.
__global__ __launch_bounds__(256) void xcat_kernel(const float* __restrict__ x,
                                                   const BF16* __restrict__ res_sp,
                                                   const float* __restrict__ clsout,
                                                   float* outbuf) {
    const int gidx = blockIdx.x;
    const int b = gidx / 3137, j = gidx - b * 3137;
    const int tid = threadIdx.x;
    if (j == 0) {
        const float* xr = x + (size_t)b * 3137 * 768;
        const float* cr = clsout + (size_t)b * 768;
#pragma unroll
        for (int i = 0; i < 3; ++i) {
            int c = tid + i * 256;
            outbuf[(size_t)gidx * 768 + c] = xr[c] + cr[c];
        }
    } else {
        const int p = j - 1, k = p >> 4, t = p & 15;
        const BF16* rs = res_sp + (size_t)((b * 16 + t) * 197 + 1 + k) * 768;
#pragma unroll
        for (int i = 0; i < 3; ++i) {
            int c = tid + i * 256;
            outbuf[(size_t)gidx * 768 + c] = outbuf[(size_t)gidx * 768 + c] + bf2f(rs[c]);
        }
    }
}

// ---------------------------------------------------------------------------
extern "C" void kernel_launch(void* const* d_in, const int* in_sizes, int n_in,
                              void* d_out, int out_size, void* d_ws, size_t ws_size,
                              hipStream_t stream) {
    const float* x       = (const float*)d_in[0];
    const float* ln1_g   = (const float*)d_in[4];
    const float* ln1_b   = (const float*)d_in[5];
    const float* lnt_g   = (const float*)d_in[6];
    const float* lnt_b   = (const float*)d_in[7];
    const float* ln2_g   = (const float*)d_in[8];
    const float* ln2_b   = (const float*)d_in[9];
    const float* lncls_g = (const float*)d_in[10];
    const float* lncls_b = (const float*)d_in[11];
    const float* Wqkv_s  = (const float*)d_in[12];
    const float* Wproj_s = (const float*)d_in[13];
    const float* bproj_s = (const float*)d_in[14];
    const float* Wqkv4   = (const float*)d_in[15];
    const float* Wqkv8   = (const float*)d_in[16];
    const float* Wqkv16  = (const float*)d_in[17];
    const float* Wp4     = (const float*)d_in[18];
    const float* bp4     = (const float*)d_in[19];
    const float* Wp8     = (const float*)d_in[20];
    const float* bp8     = (const float*)d_in[21];
    const float* Wp16    = (const float*)d_in[22];
    const float* bp16    = (const float*)d_in[23];
    const float* Wtfc    = (const float*)d_in[24];
    const float* btfc    = (const float*)d_in[25];
    const float* Wfc1    = (const float*)d_in[26];
    const float* bfc1    = (const float*)d_in[27];
    const float* Wfc2    = (const float*)d_in[28];
    const float* bfc2    = (const float*)d_in[29];
    float* out = (float*)d_out;

    // ---- workspace layout (bytes), lifetime-aliased; peak = 96,694,272 (known-good)
    const size_t oW0 = 0;               // weight slot 0 (4,718,592)
    const size_t oW1 = 4718592;         // weight slot 1 (4,718,592)
    const size_t oR1 = 9437184;         // xtn -> atts -> hln          (19,365,888)
    const size_t oR2 = 28803072;        // res_temp ; h1 spans R2..R3  (19,267,584)
    const size_t oR3 = 48070656;        // qkv chunks ; h1 tail        (29,048,832)
    const size_t oR4 = 77119488;        // att -> xsn -> res_sp        (19,365,888)
    const size_t oCL = 96485376;        // clsln fp32 (196,608)
    const size_t oCO = 96681984;        // clsout fp32 (12,288)
    const size_t NEED = 96694272;
    if (ws_size < NEED) return;
    char* ws = (char*)d_ws;

    BF16* w0       = (BF16*)(ws + oW0);
    BF16* w1       = (BF16*)(ws + oW1);
    BF16* xtn      = (BF16*)(ws + oR1);
    BF16* atts     = (BF16*)(ws + oR1);
    BF16* hln      = (BF16*)(ws + oR1);
    BF16* res_temp = (BF16*)(ws + oR2);
    BF16* h1       = (BF16*)(ws + oR2);   // 12548x1536 bf16 = 38,547,456 B (spans R2+R3 head)
    BF16* qkv      = (BF16*)(ws + oR3);
    BF16* att      = (BF16*)(ws + oR4);
    BF16* xsn      = (BF16*)(ws + oR4);
    BF16* res_sp   = (BF16*)(ws + oR4);
    float* clsln   = (float*)(ws + oCL);
    float* clsout  = (float*)(ws + oCO);

    // ---- temporal LN
    ln_kernel<0><<<12544, 256, 0, stream>>>(x, nullptr, nullptr, lnt_g, lnt_b, xtn, nullptr);

    // ---- scale 16 (2 row-chunks of 6272)
    wtrans<<<dim3(24, 72), 256, 0, stream>>>(Wqkv16, w0, 768, 2304);
    for (int c = 0; c < 2; ++c) {
        gemm_bf16<0, 0><<<dim3(18, 49), 256, 0, stream>>>(xtn + (size_t)c * 6272 * 768, w0, nullptr, nullptr, qkv, 6272, 2304, 768);
        temporal_attn<16, 256><<<4704, 256, 0, stream>>>(qkv, att + (size_t)c * 6272 * 768);
    }
    wtrans<<<dim3(24, 24), 256, 0, stream>>>(Wp16, w1, 768, 768);
    gemm_bf16<0, 1><<<dim3(6, 98), 256, 0, stream>>>(att, w1, bp16, nullptr, res_temp, 12544, 768, 768);

    // ---- scale 8
    wtrans<<<dim3(24, 72), 256, 0, stream>>>(Wqkv8, w0, 768, 2304);
    gemm_bf16<1, 0><<<dim3(18, 49), 256, 0, stream>>>(xtn, w0, nullptr, nullptr, qkv, 6272, 2304, 768);
    temporal_attn<8, 64><<<9408, 64, 0, stream>>>(qkv, att);
    wtrans<<<dim3(24, 24), 256, 0, stream>>>(Wp8, w1, 768, 768);
    gemm_bf16<0, 2><<<dim3(6, 49), 256, 0, stream>>>(att, w1, bp8, nullptr, res_temp, 6272, 768, 768);

    // ---- scale 4
    wtrans<<<dim3(24, 72), 256, 0, stream>>>(Wqkv4, w0, 768, 2304);
    gemm_bf16<2, 0><<<dim3(18, 25), 256, 0, stream>>>(xtn, w0, nullptr, nullptr, qkv, 3136, 2304, 768);
    temporal_attn<4, 64><<<9408, 64, 0, stream>>>(qkv, att);
    wtrans<<<dim3(24, 24), 256, 0, stream>>>(Wp4, w1, 768, 768);
    gemm_bf16<0, 3><<<dim3(6, 25), 256, 0, stream>>>(att, w1, bp4, nullptr, res_temp, 3136, 768, 768);

    // ---- temporal FC + x residual -> xtfull stored in d_out at x-like rows
    wtrans<<<dim3(24, 24), 256, 0, stream>>>(Wtfc, w0, 768, 768);
    gemm_bf16<0, 4><<<dim3(6, 98), 256, 0, stream>>>(res_temp, w0, btfc, x, out, 12544, 768, 768);

    // ---- spatial path (2 chunks of 32 bt-groups = 6304 rows)
    ln_kernel<1><<<12608, 256, 0, stream>>>(x, out, nullptr, ln1_g, ln1_b, xsn, nullptr);
    wtrans<<<dim3(24, 72), 256, 0, stream>>>(Wqkv_s, w1, 768, 2304);
    for (int c = 0; c < 2; ++c) {
        gemm_bf16<0, 0><<<dim3(18, 50), 256, 0, stream>>>(xsn + (size_t)c * 6304 * 768, w1, nullptr, nullptr, qkv, 6304, 2304, 768);
        spatial_attn_mfma<<<1536, 256, 0, stream>>>(qkv, atts + (size_t)c * 6304 * 768);
    }
    wtrans<<<dim3(24, 24), 256, 0, stream>>>(Wproj_s, w0, 768, 768);
    gemm_bf16<0, 1><<<dim3(6, 99), 256, 0, stream>>>(atts, w0, bproj_s, nullptr, res_sp, 12608, 768, 768);

    // ---- cls path
    ln_kernel<3><<<64, 256, 0, stream>>>(nullptr, nullptr, res_sp, lncls_g, lncls_b, nullptr, clsln);
    cls_attn_kernel<<<4, 256, 0, stream>>>(clsln, clsout);

    // ---- combine (in-place in d_out)
    xcat_kernel<<<12548, 256, 0, stream>>>(x, res_sp, clsout, out);
    ln_kernel<2><<<12548, 256, 0, stream>>>(out, nullptr, nullptr, ln2_g, ln2_b, hln, nullptr);

    // ---- MLP: full-M, hidden split in 2 halves; fc2 accumulates into d_out
    wtrans<<<dim3(24, 96), 256, 0, stream>>>(Wfc1, w0, 768, 3072);          // w0 = Wfc1t [3072,768]
    wtrans<<<dim3(48, 24), 256, 0, stream>>>(Wfc2, w1, 1536, 768);          // w1a [768,1536]
    wtrans<<<dim3(48, 24), 256, 0, stream>>>(Wfc2 + (size_t)1536 * 768, w1 + (size_t)768 * 1536, 1536, 768);  // w1b

    // half a
    gemm_bf16<0, 6><<<dim3(12, 99), 256, 0, stream>>>(hln, w0, bfc1, nullptr, h1, 12548, 1536, 768);
    gemm_bf16<0, 7><<<dim3(6, 99), 256, 0, stream>>>(h1, w1, bfc2, out, out, 12548, 768, 1536);
    // half b
    gemm_bf16<0, 6><<<dim3(12, 99), 256, 0, stream>>>(hln, w0 + (size_t)1536 * 768, bfc1 + 1536, nullptr, h1, 12548, 1536, 768);
    gemm_bf16<0, 8><<<dim3(6, 99), 256, 0, stream>>>(h1, w1 + (size_t)768 * 1536, nullptr, out, out, 12548, 768, 1536);
}